// Round 5
// baseline (586.663 us; speedup 1.0000x reference)
//
#include <hip/hip_runtime.h>
#include <cstdint>
#include <cstddef>

// ---------------------------------------------------------------------------
// GCN forward on MI355X.
// R9: collapse launch count. Dispatch-sum vs wall-clock across R6-R8 shows a
//     consistent ~15us fixed overhead per launch (~180us over 12 launches).
//     Fuse the 6-kernel CSR build + gemm256 into ONE kernel: blocks 0..255
//     run hist->scan->base->scatter->csr/outdeg with spin-barriers among
//     build blocks only; blocks 256..1535 run gemm256 tiles concurrently
//     (never wait -> deadlock-free at any occupancy). c_src scaling moves
//     back to agg1 per-edge (c_src isn't ready during the overlapped gemm).
//     prep_weights zeroes the barrier counters. 12 launches -> 6.
// ---------------------------------------------------------------------------

#define NPB 128        // nodes per bucket
#define BSHIFT 7
#define NBLD 256       // build-role blocks in mega kernel
#define GEMM_G 1536    // mega grid size

typedef __attribute__((ext_vector_type(8))) short short8;
typedef __attribute__((ext_vector_type(4))) float f32x4;

static __device__ __forceinline__ float4 ld4(const float* p) { return *(const float4*)p; }

static __device__ __forceinline__ float bf2f(unsigned int u) {
  union { unsigned int i; float f; } x; x.i = u << 16; return x.f;
}
static __device__ __forceinline__ unsigned int f2bf(float f) {
  union { float f; unsigned int i; } x; x.f = f;
  unsigned int r = x.i + 0x7fff + ((x.i >> 16) & 1);  // RTN-even
  return r >> 16;
}

// spin-barrier among the NBLD build blocks (gemm blocks never touch it)
static __device__ __forceinline__ void bbar(int* ctr, int expected) {
  __syncthreads();
  if (threadIdx.x == 0) {
    __threadfence();
    atomicAdd(ctr, 1);
    while (atomicAdd(ctr, 0) < expected) __builtin_amdgcn_s_sleep(8);
  }
  __syncthreads();
  __threadfence();
}

// ---- weight prep (also zeroes spin-barrier counters) ----------------------
__global__ __launch_bounds__(256) void prep_weights(const float* __restrict__ W0,
                                                    const float* __restrict__ W1,
                                                    ushort* __restrict__ W0t,
                                                    ushort* __restrict__ W1t,
                                                    int* __restrict__ bar) {
  int t = blockIdx.x * 256 + threadIdx.x;
  if (t < 8) bar[t] = 0;
  if (t < 128 * 256) {
    int nn = t >> 8, kk = t & 255;
    W0t[nn * 256 + kk] = (ushort)f2bf(W0[kk * 128 + nn]);
  }
  if (t < 128 * 128) {
    int nn = t >> 7, kk = t & 127;
    W1t[nn * 128 + kk] = (ushort)f2bf(W1[kk * 128 + nn]);
  }
}

// ---------------------------------------------------------------------------
// MEGA: build role (bid<NBLD): hist -> bucket scans -> base -> scatter ->
//       per-bucket csr fill + outdeg/c_src.  Spin barriers bar[0..3].
//       gemm role (bid>=NBLD): t0b[n,128](bf16) = x[n,256] @ W0 (NO c_src).
// ---------------------------------------------------------------------------
__global__ __launch_bounds__(256) void mega(
    const int* src, const int* dst,
    int* bhD, int* bhS, int* totD, int* totS, int* baseD, int* baseS,
    unsigned int* ebufD, uint8_t* ebufS, int* row_start, int* csr, float* c_src,
    const float* x, const ushort* W0t, ushort* t0b,
    int* bar, int n, int E, int nbk, int ept, int ngemm) {
  __shared__ alignas(16) union {
    struct { ushort As[64 * 64]; ushort Bs[128 * 64]; } g;   // 24 KB (gemm)
    struct { int a[1024]; int b[1024]; } h;                  // hist / cursors
    int scan[1024];                                          // scans
    struct { int cnt[NPB]; int sc[NPB]; int cur[NPB]; int cntS[NPB]; } cb;
  } sm;
  int bid = blockIdx.x, t = threadIdx.x;

  if (bid >= NBLD) {  // ================= gemm role =================
    int lane = t & 63;
    int w = t >> 6;
    int l16 = lane & 15, hi = lane >> 4;
    for (int tile = bid - NBLD; tile < ngemm; tile += GEMM_G - NBLD) {
      int row0 = tile * 64;
      f32x4 acc[8];
#pragma unroll
      for (int c = 0; c < 8; c++) acc[c] = (f32x4){0.f, 0.f, 0.f, 0.f};
      for (int kt = 0; kt < 256; kt += 64) {
        {  // stage A: fp32 x -> bf16 LDS, swizzled
          int r = t >> 2;
          int gr = row0 + r;
#pragma unroll
          for (int u = 0; u < 2; u++) {
            int c8 = (t & 3) * 2 + u;
            float4 v0 = make_float4(0.f, 0.f, 0.f, 0.f), v1 = v0;
            if (gr < n) {
              v0 = ld4(&x[(size_t)gr * 256 + kt + c8 * 8]);
              v1 = ld4(&x[(size_t)gr * 256 + kt + c8 * 8 + 4]);
            }
            uint4 o;
            o.x = f2bf(v0.x) | (f2bf(v0.y) << 16);
            o.y = f2bf(v0.z) | (f2bf(v0.w) << 16);
            o.z = f2bf(v1.x) | (f2bf(v1.y) << 16);
            o.w = f2bf(v1.z) | (f2bf(v1.w) << 16);
            *(uint4*)&sm.g.As[r * 64 + (c8 ^ (r & 7)) * 8] = o;
          }
        }
        {  // stage B from W0t (bf16)
          int r = t >> 1;
#pragma unroll
          for (int u = 0; u < 4; u++) {
            int c8 = (t & 1) * 4 + u;
            uint4 o = *(const uint4*)&W0t[(size_t)r * 256 + kt + c8 * 8];
            *(uint4*)&sm.g.Bs[r * 64 + (c8 ^ (r & 7)) * 8] = o;
          }
        }
        __syncthreads();
#pragma unroll
        for (int ks = 0; ks < 2; ks++) {
          int ar = w * 16 + l16;
          int ac = ks * 4 + hi;
          short8 a = *(const short8*)&sm.g.As[ar * 64 + (ac ^ (ar & 7)) * 8];
#pragma unroll
          for (int c = 0; c < 8; c++) {
            int br = c * 16 + l16;
            short8 b = *(const short8*)&sm.g.Bs[br * 64 + (ac ^ (br & 7)) * 8];
            acc[c] = __builtin_amdgcn_mfma_f32_16x16x32_bf16(a, b, acc[c], 0, 0, 0);
          }
        }
        __syncthreads();
      }
#pragma unroll
      for (int c = 0; c < 8; c++)
#pragma unroll
        for (int r = 0; r < 4; r++) {
          int gm = row0 + w * 16 + hi * 4 + r;
          if (gm < n) t0b[(size_t)gm * 128 + c * 16 + l16] = (ushort)f2bf(acc[c][r]);
        }
    }
    return;
  }

  // ================= build role =================
  int base0 = bid * 256 * ept + t;
  // P0: per-block bucket histograms
  for (int i = t; i < nbk; i += 256) { sm.h.a[i] = 0; sm.h.b[i] = 0; }
  __syncthreads();
  for (int j = 0; j < ept; j++) {
    int e = base0 + j * 256;
    if (e < E) {
      atomicAdd(&sm.h.a[dst[e] >> BSHIFT], 1);
      atomicAdd(&sm.h.b[src[e] >> BSHIFT], 1);
    }
  }
  __syncthreads();
  for (int i = t; i < nbk; i += 256) {
    bhD[(size_t)bid * nbk + i] = sm.h.a[i];
    bhS[(size_t)bid * nbk + i] = sm.h.b[i];
  }
  bbar(&bar[0], NBLD);

  // P1: per-bucket exclusive scan across the NBLD block-histograms
  for (int c = bid; c < nbk; c += NBLD) {
    int v = bhD[(size_t)t * nbk + c];
    sm.scan[t] = v;
    __syncthreads();
    for (int off = 1; off < 256; off <<= 1) {
      int u = (t >= off) ? sm.scan[t - off] : 0;
      __syncthreads();
      sm.scan[t] += u;
      __syncthreads();
    }
    bhD[(size_t)t * nbk + c] = sm.scan[t] - v;
    if (t == 255) totD[c] = sm.scan[255];
    __syncthreads();
    int w2 = bhS[(size_t)t * nbk + c];
    sm.scan[t] = w2;
    __syncthreads();
    for (int off = 1; off < 256; off <<= 1) {
      int u = (t >= off) ? sm.scan[t - off] : 0;
      __syncthreads();
      sm.scan[t] += u;
      __syncthreads();
    }
    bhS[(size_t)t * nbk + c] = sm.scan[t] - w2;
    if (t == 255) totS[c] = sm.scan[255];
    __syncthreads();
  }
  bbar(&bar[1], NBLD);

  // P2: exclusive scan over bucket totals (block 0 only)
  if (bid == 0) {
#pragma unroll
    for (int side = 0; side < 2; side++) {
      const int* tot = side ? totS : totD;
      int* bse = side ? baseS : baseD;
      int v[4];
      int s = 0;
#pragma unroll
      for (int j = 0; j < 4; j++) {
        int idx = t * 4 + j;
        v[j] = (idx < nbk) ? tot[idx] : 0;
        s += v[j];
      }
      sm.scan[t] = s;
      __syncthreads();
      for (int off = 1; off < 256; off <<= 1) {
        int u = (t >= off) ? sm.scan[t - off] : 0;
        __syncthreads();
        sm.scan[t] += u;
        __syncthreads();
      }
      int run = sm.scan[t] - s;
#pragma unroll
      for (int j = 0; j < 4; j++) {
        int idx = t * 4 + j;
        if (idx < nbk) bse[idx] = run;
        run += v[j];
      }
      if (t == 255) bse[nbk] = run;
      __syncthreads();
    }
  }
  bbar(&bar[2], NBLD);

  // P3: scatter edges into bucket segments (LDS cursors)
  for (int i = t; i < nbk; i += 256) {
    sm.h.a[i] = baseD[i] + bhD[(size_t)bid * nbk + i];
    sm.h.b[i] = baseS[i] + bhS[(size_t)bid * nbk + i];
  }
  __syncthreads();
  for (int j = 0; j < ept; j++) {
    int e = base0 + j * 256;
    if (e < E) {
      int s = src[e], d = dst[e];
      int pD = atomicAdd(&sm.h.a[d >> BSHIFT], 1);
      ebufD[pD] = ((unsigned int)(d & (NPB - 1)) << 17) | (unsigned int)s;
      int pS = atomicAdd(&sm.h.b[s >> BSHIFT], 1);
      ebufS[pS] = (uint8_t)(s & (NPB - 1));
    }
  }
  bbar(&bar[3], NBLD);

  // P4: per-bucket csr fill + row_start + outdeg/c_src
  for (int bk = bid; bk < nbk; bk += NBLD) {
    if (t < NPB) { sm.cb.cnt[t] = 0; sm.cb.cntS[t] = 0; }
    __syncthreads();
    int s0 = baseD[bk], s1 = baseD[bk + 1];
    for (int i = s0 + t; i < s1; i += 256) atomicAdd(&sm.cb.cnt[ebufD[i] >> 17], 1);
    int u0 = baseS[bk], u1 = baseS[bk + 1];
    for (int i = u0 + t; i < u1; i += 256) atomicAdd(&sm.cb.cntS[ebufS[i]], 1);
    __syncthreads();
    int c = (t < NPB) ? sm.cb.cnt[t] : 0;
    if (t < NPB) sm.cb.sc[t] = c;
    __syncthreads();
    for (int off = 1; off < NPB; off <<= 1) {
      int u = (t < NPB && t >= off) ? sm.cb.sc[t - off] : 0;
      __syncthreads();
      if (t < NPB) sm.cb.sc[t] += u;
      __syncthreads();
    }
    if (t < NPB) {
      int start = s0 + sm.cb.sc[t] - c;
      sm.cb.cur[t] = start;
      int node = bk * NPB + t;
      if (node < n) {
        row_start[node] = start;
        c_src[node] = rsqrtf(fmaxf((float)sm.cb.cntS[t], 1.0f));
      }
    }
    if (bk == 0 && t == 0) row_start[n] = baseD[nbk];
    __syncthreads();
    for (int i = s0 + t; i < s1; i += 256) {
      unsigned int wv = ebufD[i];
      int p = atomicAdd(&sm.cb.cur[wv >> 17], 1);
      csr[p] = (int)(wv & 0x1FFFFu);
    }
    __syncthreads();
  }
}

// t1b[n,128](bf16) = (h1b[n,128](bf16) @ W1) * c_src[row]   (MFMA)
__global__ __launch_bounds__(256) void gemm128_mfma(const ushort* __restrict__ A,
                                                    const ushort* __restrict__ W1t,
                                                    const float* __restrict__ c_src,
                                                    ushort* __restrict__ Y, int n) {
  __shared__ alignas(16) ushort As[64 * 64];    // 8 KB
  __shared__ alignas(16) ushort Bs[128 * 64];   // 16 KB
  int tid = threadIdx.x;
  int row0 = blockIdx.x * 64;
  int lane = tid & 63;
  int w = tid >> 6;
  int l16 = lane & 15, hi = lane >> 4;
  f32x4 acc[8];
#pragma unroll
  for (int c = 0; c < 8; c++) acc[c] = (f32x4){0.f, 0.f, 0.f, 0.f};

  for (int kt = 0; kt < 128; kt += 64) {
    {  // stage A (already bf16)
      int r = tid >> 2;
      int gr = row0 + r;
#pragma unroll
      for (int u = 0; u < 2; u++) {
        int c8 = (tid & 3) * 2 + u;
        uint4 o = make_uint4(0u, 0u, 0u, 0u);
        if (gr < n) o = *(const uint4*)&A[(size_t)gr * 128 + kt + c8 * 8];
        *(uint4*)&As[r * 64 + (c8 ^ (r & 7)) * 8] = o;
      }
    }
    {  // stage B from W1t
      int r = tid >> 1;
#pragma unroll
      for (int u = 0; u < 4; u++) {
        int c8 = (tid & 1) * 4 + u;
        uint4 o = *(const uint4*)&W1t[(size_t)r * 128 + kt + c8 * 8];
        *(uint4*)&Bs[r * 64 + (c8 ^ (r & 7)) * 8] = o;
      }
    }
    __syncthreads();
#pragma unroll
    for (int ks = 0; ks < 2; ks++) {
      int ar = w * 16 + l16;
      int ac = ks * 4 + hi;
      short8 a = *(const short8*)&As[ar * 64 + (ac ^ (ar & 7)) * 8];
#pragma unroll
      for (int c = 0; c < 8; c++) {
        int br = c * 16 + l16;
        short8 b = *(const short8*)&Bs[br * 64 + (ac ^ (br & 7)) * 8];
        acc[c] = __builtin_amdgcn_mfma_f32_16x16x32_bf16(a, b, acc[c], 0, 0, 0);
      }
    }
    __syncthreads();
  }
  float cs[4];
#pragma unroll
  for (int r = 0; r < 4; r++) {
    int gm = row0 + w * 16 + hi * 4 + r;
    cs[r] = (gm < n) ? c_src[gm] : 0.f;
  }
#pragma unroll
  for (int c = 0; c < 8; c++)
#pragma unroll
    for (int r = 0; r < 4; r++) {
      int gm = row0 + w * 16 + hi * 4 + r;
      if (gm < n) Y[(size_t)gm * 128 + c * 16 + l16] = (ushort)f2bf(acc[c][r] * cs[r]);
    }
}

// ---------------------------------------------------------------------------
// Persistent-wave aggregation (R8 structure).  SCALE: multiply each gathered
// row by c_src[s] (s and c_src[s] broadcast via __shfl from the lane that
// cooperatively loaded them -- one extra 4B gather per EDGE, not per lane).
// ---------------------------------------------------------------------------
template <bool RELU, bool SCALE, bool OUT_BF16>
__global__ __launch_bounds__(256) void agg_kernel(const ushort* __restrict__ T,
                                                  const int* __restrict__ row_start,
                                                  const int* __restrict__ csr_src,
                                                  const float* __restrict__ c_src,
                                                  const float* __restrict__ bias,
                                                  void* __restrict__ out, int n) {
  int lane = threadIdx.x & 63;
  int gw = (blockIdx.x * 256 + threadIdx.x) >> 6;
  int nw = gridDim.x * 4;
  float bx = bias[lane * 2], by = bias[lane * 2 + 1];
  for (int node = gw; node < n; node += nw) {
    int e0 = row_start[node], e1 = row_start[node + 1];
    float ax = 0.f, ay = 0.f;
    for (int eb = e0; eb < e1; eb += 64) {
      int rem = e1 - eb;
      int cnt = rem < 64 ? rem : 64;
      int msrc = (lane < rem) ? csr_src[eb + lane] : 0;
      float mcs = 1.f;
      if (SCALE) mcs = (lane < rem) ? c_src[msrc] : 0.f;
      int j = 0;
      for (; j + 7 < cnt; j += 8) {
        unsigned int w[8];
        float cs8[8];
#pragma unroll
        for (int u = 0; u < 8; u++) {
          int s = __shfl(msrc, j + u);
          if (SCALE) cs8[u] = __shfl(mcs, j + u);
          w[u] = *(const unsigned int*)&T[(size_t)s * 128 + lane * 2];
        }
#pragma unroll
        for (int u = 0; u < 8; u++) {
          if (SCALE) {
            ax = fmaf(bf2f(w[u] & 0xffff), cs8[u], ax);
            ay = fmaf(bf2f(w[u] >> 16), cs8[u], ay);
          } else {
            ax += bf2f(w[u] & 0xffff);
            ay += bf2f(w[u] >> 16);
          }
        }
      }
      for (; j < cnt; j++) {
        int s = __shfl(msrc, j);
        float cs = SCALE ? __shfl(mcs, j) : 1.f;
        unsigned int w0 = *(const unsigned int*)&T[(size_t)s * 128 + lane * 2];
        if (SCALE) {
          ax = fmaf(bf2f(w0 & 0xffff), cs, ax);
          ay = fmaf(bf2f(w0 >> 16), cs, ay);
        } else {
          ax += bf2f(w0 & 0xffff);
          ay += bf2f(w0 >> 16);
        }
      }
    }
    float cd = rsqrtf(fmaxf((float)(e1 - e0), 1.0f));
    float rx = fmaf(ax, cd, bx);
    float ry = fmaf(ay, cd, by);
    if (RELU) { rx = fmaxf(rx, 0.f); ry = fmaxf(ry, 0.f); }
    if (OUT_BF16) {
      ((unsigned int*)out)[(size_t)node * 64 + lane] = f2bf(rx) | (f2bf(ry) << 16);
    } else {
      float2 r2; r2.x = rx; r2.y = ry;
      ((float2*)out)[(size_t)node * 64 + lane] = r2;
    }
  }
}

// logits[n,40] = relu(H[n,128]) @ Wc[128,40] + bc
__global__ __launch_bounds__(256) void logits_kernel(const float* __restrict__ H,
                                                     const float* __restrict__ Wc,
                                                     const float* __restrict__ bc,
                                                     float* __restrict__ out, int n) {
  __shared__ float Wl[128 * 40];
  for (int i = threadIdx.x; i < 128 * 40; i += 256) Wl[i] = Wc[i];
  __syncthreads();
  int rl = threadIdx.x >> 3;
  int cg = threadIdx.x & 7;
  int r = blockIdx.x * 32 + rl;
  if (r >= n) return;
  float acc[5] = {0.f, 0.f, 0.f, 0.f, 0.f};
  const float* hr = &H[(size_t)r * 128];
  for (int k = 0; k < 128; k++) {
    float v = fmaxf(hr[k], 0.f);
#pragma unroll
    for (int j = 0; j < 5; j++) acc[j] = fmaf(v, Wl[k * 40 + cg * 5 + j], acc[j]);
  }
#pragma unroll
  for (int j = 0; j < 5; j++) out[(size_t)r * 40 + cg * 5 + j] = acc[j] + bc[cg * 5 + j];
}

extern "C" void kernel_launch(void* const* d_in, const int* in_sizes, int n_in,
                              void* d_out, int out_size, void* d_ws, size_t ws_size,
                              hipStream_t stream) {
  const float* x = (const float*)d_in[0];
  const int* src = (const int*)d_in[1];
  const int* dst = (const int*)d_in[2];
  const float* W0 = (const float*)d_in[3];
  const float* b0 = (const float*)d_in[4];
  const float* W1 = (const float*)d_in[5];
  const float* b1 = (const float*)d_in[6];
  const float* Wc = (const float*)d_in[7];
  const float* bc = (const float*)d_in[8];
  const int n = in_sizes[0] / 256;
  const int E = in_sizes[1];
  const int nbk = (n + NPB - 1) >> BSHIFT;                 // 782 (<=1024)
  const int ept = (E + NBLD * 256 - 1) / (NBLD * 256);     // 25

  char* wsp = (char*)d_ws;
  auto alloc = [&](size_t bytes) -> char* {
    char* p = wsp;
    wsp += (bytes + 255) & ~(size_t)255;
    return p;
  };
  ushort* t0b = (ushort*)alloc((size_t)n * 128 * sizeof(ushort));  // t0 / reused as t1
  ushort* h1b = (ushort*)alloc((size_t)n * 128 * sizeof(ushort));
  float* c_src = (float*)alloc((size_t)n * sizeof(float));
  ushort* W0t = (ushort*)alloc((size_t)128 * 256 * sizeof(ushort));
  ushort* W1t = (ushort*)alloc((size_t)128 * 128 * sizeof(ushort));
  int* bhD = (int*)alloc((size_t)NBLD * nbk * sizeof(int));
  int* bhS = (int*)alloc((size_t)NBLD * nbk * sizeof(int));
  int* totD = (int*)alloc((size_t)nbk * sizeof(int));
  int* totS = (int*)alloc((size_t)nbk * sizeof(int));
  int* baseD = (int*)alloc((size_t)(nbk + 1) * sizeof(int));
  int* baseS = (int*)alloc((size_t)(nbk + 1) * sizeof(int));
  unsigned int* ebufD = (unsigned int*)alloc((size_t)E * sizeof(unsigned int));
  uint8_t* ebufS = (uint8_t*)alloc((size_t)E);
  int* row_start = (int*)alloc((size_t)(n + 1) * sizeof(int));
  int* csr = (int*)alloc((size_t)E * sizeof(int));
  int* bar = (int*)alloc((size_t)8 * sizeof(int));

  float* h_out = (float*)d_out;             // n x 128 (h2)
  float* logits = h_out + (size_t)n * 128;  // n x 40

  const int ngemm = (n + 63) / 64;          // 1563

  // 1) weight transpose+cast, zero barriers
  prep_weights<<<128, 256, 0, stream>>>(W0, W1, W0t, W1t, bar);
  // 2) fused CSR build (blocks 0..255, spin-barred) || gemm256 (blocks 256..)
  mega<<<GEMM_G, 256, 0, stream>>>(src, dst, bhD, bhS, totD, totS, baseD, baseS,
                                   ebufD, ebufS, row_start, csr, c_src,
                                   x, W0t, t0b, bar, n, E, nbk, ept, ngemm);
  // 3) h1b(bf16) = relu(agg(t0b * c_src[s]) * c_dst + b0)
  agg_kernel<true, true, true><<<2048, 256, 0, stream>>>(
      t0b, row_start, csr, c_src, b0, (void*)h1b, n);
  // 4) t1b(bf16) = (h1b @ W1) * c_src   (reuse t0b buffer)
  gemm128_mfma<<<(n + 63) / 64, 256, 0, stream>>>(h1b, W1t, c_src, t0b, n);
  // 5) h2(fp32, d_out) = agg(t1b) * c_dst + b1
  agg_kernel<false, false, false><<<2048, 256, 0, stream>>>(
      t0b, row_start, csr, c_src, b1, (void*)h_out, n);
  // 6) logits = relu(h2) @ Wc + bc
  logits_kernel<<<(n + 31) / 32, 256, 0, stream>>>(h_out, Wc, bc, logits, n);
}

// Round 6
// 467.068 us; speedup vs baseline: 1.2561x; 1.2561x over previous
//
#include <hip/hip_runtime.h>
#include <cstdint>
#include <cstddef>

// ---------------------------------------------------------------------------
// GCN forward on MI355X.
// R10: revert R9's mega fusion (spin-barrier RMW polling + 1-block/CU build
//      phases caused 280us of stall). Mega's counters exposed the true cost:
//      the CSR build was ~250us all along (launch overhead is only ~4us).
//      Root cause: scatter writes per-edge through per-bucket cursors ->
//      64 lanes hit 64 different bucket segments -> ~64 lines per store
//      (WRITE_SIZE 128MB vs 42MB logical). Fix: block-local LDS counting
//      sort -- place the block's 6400 edges bucket-sorted in LDS, then
//      stream out with consecutive lanes -> consecutive addresses
//      (dest = binBase[bucket]+slot, bucket via 10-step LDS binary search).
//      csr-fill + outdeg merged into one bucket-parallel kernel.
// ---------------------------------------------------------------------------

#define NPB 128        // nodes per bucket
#define BSHIFT 7
#define EPT3 25
#define CHUNK (EPT3 * 256)   // 6400 edges per build block

typedef __attribute__((ext_vector_type(8))) short short8;
typedef __attribute__((ext_vector_type(4))) float f32x4;

static __device__ __forceinline__ float4 ld4(const float* p) { return *(const float4*)p; }

static __device__ __forceinline__ float bf2f(unsigned int u) {
  union { unsigned int i; float f; } x; x.i = u << 16; return x.f;
}
static __device__ __forceinline__ unsigned int f2bf(float f) {
  union { float f; unsigned int i; } x; x.f = f;
  unsigned int r = x.i + 0x7fff + ((x.i >> 16) & 1);  // RTN-even
  return r >> 16;
}

// ---- weight prep: W0t[n][k]=bf16(W0[k][n]) (128x256), W1t (128x128) -------
__global__ __launch_bounds__(256) void prep_weights(const float* __restrict__ W0,
                                                    const float* __restrict__ W1,
                                                    ushort* __restrict__ W0t,
                                                    ushort* __restrict__ W1t) {
  int t = blockIdx.x * 256 + threadIdx.x;
  if (t < 128 * 256) {
    int nn = t >> 8, kk = t & 255;
    W0t[nn * 256 + kk] = (ushort)f2bf(W0[kk * 128 + nn]);
  }
  if (t < 128 * 128) {
    int nn = t >> 7, kk = t & 127;
    W1t[nn * 128 + kk] = (ushort)f2bf(W1[kk * 128 + nn]);
  }
}

// ---- K1: per-block bucket histograms (dst-key and src-key) ----------------
__global__ __launch_bounds__(256) void bucket_hist(const int* __restrict__ src,
                                                   const int* __restrict__ dst,
                                                   int* __restrict__ bhD, int* __restrict__ bhS,
                                                   int E, int nbk) {
  __shared__ int hD[1024], hS[1024];
  int t = threadIdx.x;
  for (int i = t; i < nbk; i += 256) { hD[i] = 0; hS[i] = 0; }
  __syncthreads();
  int base = blockIdx.x * CHUNK + t;
  for (int j = 0; j < EPT3; j++) {
    int e = base + j * 256;
    if (e < E) {
      atomicAdd(&hD[dst[e] >> BSHIFT], 1);
      atomicAdd(&hS[src[e] >> BSHIFT], 1);
    }
  }
  __syncthreads();
  for (int i = t; i < nbk; i += 256) {
    bhD[(size_t)blockIdx.x * nbk + i] = hD[i];
    bhS[(size_t)blockIdx.x * nbk + i] = hS[i];
  }
}

// ---- K2a: per-bucket exclusive scan across the nblk edge-blocks -----------
__global__ __launch_bounds__(256) void bucket_scan_blocks(int* __restrict__ bhD,
                                                          int* __restrict__ bhS,
                                                          int* __restrict__ totD,
                                                          int* __restrict__ totS,
                                                          int nbk, int nblk) {
  __shared__ int lds[256];
  int b = blockIdx.x, t = threadIdx.x;
  int v = (t < nblk) ? bhD[(size_t)t * nbk + b] : 0;
  lds[t] = v;
  __syncthreads();
  for (int off = 1; off < 256; off <<= 1) {
    int u = (t >= off) ? lds[t - off] : 0;
    __syncthreads();
    lds[t] += u;
    __syncthreads();
  }
  if (t < nblk) bhD[(size_t)t * nbk + b] = lds[t] - v;  // exclusive
  if (t == 255) totD[b] = lds[255];
  __syncthreads();
  int w = (t < nblk) ? bhS[(size_t)t * nbk + b] : 0;
  lds[t] = w;
  __syncthreads();
  for (int off = 1; off < 256; off <<= 1) {
    int u = (t >= off) ? lds[t - off] : 0;
    __syncthreads();
    lds[t] += u;
    __syncthreads();
  }
  if (t < nblk) bhS[(size_t)t * nbk + b] = lds[t] - w;
  if (t == 255) totS[b] = lds[255];
}

// ---- K2b: exclusive scan over bucket totals (nbk <= 1024) -----------------
__global__ __launch_bounds__(1024) void bucket_base(const int* __restrict__ totD,
                                                    const int* __restrict__ totS,
                                                    int* __restrict__ baseD,
                                                    int* __restrict__ baseS, int nbk) {
  __shared__ int lds[1024];
  int t = threadIdx.x;
  int v = (t < nbk) ? totD[t] : 0;
  lds[t] = v;
  __syncthreads();
  for (int off = 1; off < 1024; off <<= 1) {
    int u = (t >= off) ? lds[t - off] : 0;
    __syncthreads();
    lds[t] += u;
    __syncthreads();
  }
  if (t < nbk) baseD[t] = lds[t] - v;
  if (t == 1023) baseD[nbk] = lds[1023];
  __syncthreads();
  int w = (t < nbk) ? totS[t] : 0;
  lds[t] = w;
  __syncthreads();
  for (int off = 1; off < 1024; off <<= 1) {
    int u = (t >= off) ? lds[t - off] : 0;
    __syncthreads();
    lds[t] += u;
    __syncthreads();
  }
  if (t < nbk) baseS[t] = lds[t] - w;
  if (t == 1023) baseS[nbk] = lds[1023];
}

// ---- K3: block-local LDS counting sort + coalesced scatter ----------------
// ebufD word: bits[23:17]=dst&127, bits[16:0]=src   (n < 2^17)
__global__ __launch_bounds__(256) void sort_scatter(
    const int* __restrict__ src, const int* __restrict__ dst,
    const int* __restrict__ bhD, const int* __restrict__ bhS,
    const int* __restrict__ baseD, const int* __restrict__ baseS,
    unsigned int* __restrict__ ebufD, uint8_t* __restrict__ ebufS,
    int E, int nbk) {
  __shared__ int binD[1024], binS[1024];   // hist -> lstart -> cursors -> cumulative
  __shared__ int bbD[1024], bbS[1024];     // global base - lstart (dest = bb + slot)
  __shared__ int scanT[256];
  __shared__ unsigned int sortD[CHUNK];    // 25.6 KB
  __shared__ uint8_t sortS[CHUNK];         // 6.4 KB
  int bid = blockIdx.x, t = threadIdx.x;
  int base0 = bid * CHUNK;
  int cc = min(CHUNK, E - base0);
  // phase a: local bucket hist
  for (int i = t; i < 1024; i += 256) { binD[i] = 0; binS[i] = 0; }
  __syncthreads();
  for (int j = 0; j < EPT3; j++) {
    int e = base0 + j * 256 + t;
    if (e < E) {
      atomicAdd(&binD[dst[e] >> BSHIFT], 1);
      atomicAdd(&binS[src[e] >> BSHIFT], 1);
    }
  }
  __syncthreads();
  // phase b: in-block exclusive scan of both hists (4 bins/thread over 1024)
  {
    int v[4]; int s = 0;
#pragma unroll
    for (int j = 0; j < 4; j++) { v[j] = binD[t * 4 + j]; s += v[j]; }
    scanT[t] = s;
    __syncthreads();
    for (int off = 1; off < 256; off <<= 1) {
      int u = (t >= off) ? scanT[t - off] : 0;
      __syncthreads();
      scanT[t] += u;
      __syncthreads();
    }
    int run = scanT[t] - s;
#pragma unroll
    for (int j = 0; j < 4; j++) { binD[t * 4 + j] = run; run += v[j]; }
    __syncthreads();
    s = 0;
#pragma unroll
    for (int j = 0; j < 4; j++) { v[j] = binS[t * 4 + j]; s += v[j]; }
    scanT[t] = s;
    __syncthreads();
    for (int off = 1; off < 256; off <<= 1) {
      int u = (t >= off) ? scanT[t - off] : 0;
      __syncthreads();
      scanT[t] += u;
      __syncthreads();
    }
    run = scanT[t] - s;
#pragma unroll
    for (int j = 0; j < 4; j++) { binS[t * 4 + j] = run; run += v[j]; }
    __syncthreads();
  }
  // phase b2: dest base per bin (before cursors advance)
  for (int i = t; i < nbk; i += 256) {
    bbD[i] = baseD[i] + bhD[(size_t)bid * nbk + i] - binD[i];
    bbS[i] = baseS[i] + bhS[(size_t)bid * nbk + i] - binS[i];
  }
  __syncthreads();
  // phase c: place edges into LDS sorted by bucket (cursors = binD/binS)
  for (int j = 0; j < EPT3; j++) {
    int e = base0 + j * 256 + t;
    if (e < E) {
      int s = src[e], d = dst[e];
      int pD = atomicAdd(&binD[d >> BSHIFT], 1);
      sortD[pD] = ((unsigned int)(d & (NPB - 1)) << 17) | (unsigned int)s;
      int pS = atomicAdd(&binS[s >> BSHIFT], 1);
      sortS[pS] = (uint8_t)(s & (NPB - 1));
    }
  }
  __syncthreads();
  // binD/binS are now inclusive cumulative counts (lstart[b]+cnt[b]).
  // phase d: coalesced writeout; bucket of slot i via 10-step binary search.
  for (int i = t; i < cc; i += 256) {
    int b = 0;
#pragma unroll
    for (int step = 512; step; step >>= 1)
      if (b + step <= nbk && binD[b + step - 1] <= i) b += step;
    ebufD[bbD[b] + i] = sortD[i];
    int b2 = 0;
#pragma unroll
    for (int step = 512; step; step >>= 1)
      if (b2 + step <= nbk && binS[b2 + step - 1] <= i) b2 += step;
    ebufS[bbS[b2] + i] = sortS[i];
  }
}

// ---- K4: per dst-bucket csr fill + row_start + outdeg/c_src ---------------
__global__ __launch_bounds__(256) void csr_outdeg(
    const unsigned int* __restrict__ ebufD, const uint8_t* __restrict__ ebufS,
    const int* __restrict__ baseD, const int* __restrict__ baseS,
    int* __restrict__ row_start, int* __restrict__ csr,
    float* __restrict__ c_src, int n, int nbk) {
  __shared__ int cnt[NPB], sc[NPB], cur[NPB], cntS[NPB];
  int b = blockIdx.x, t = threadIdx.x;
  if (t < NPB) { cnt[t] = 0; cntS[t] = 0; }
  __syncthreads();
  int s0 = baseD[b], s1 = baseD[b + 1];
  for (int i = s0 + t; i < s1; i += 256) atomicAdd(&cnt[ebufD[i] >> 17], 1);
  int u0 = baseS[b], u1 = baseS[b + 1];
  for (int i = u0 + t; i < u1; i += 256) atomicAdd(&cntS[ebufS[i]], 1);
  __syncthreads();
  int c = (t < NPB) ? cnt[t] : 0;
  if (t < NPB) sc[t] = c;
  __syncthreads();
  for (int off = 1; off < NPB; off <<= 1) {
    int u = (t < NPB && t >= off) ? sc[t - off] : 0;
    __syncthreads();
    if (t < NPB) sc[t] += u;
    __syncthreads();
  }
  if (t < NPB) {
    int start = s0 + sc[t] - c;  // exclusive
    cur[t] = start;
    int node = b * NPB + t;
    if (node < n) {
      row_start[node] = start;
      c_src[node] = rsqrtf(fmaxf((float)cntS[t], 1.0f));
    }
  }
  if (b == 0 && t == 0) row_start[n] = baseD[nbk];
  __syncthreads();
  for (int i = s0 + t; i < s1; i += 256) {
    unsigned int wv = ebufD[i];
    int p = atomicAdd(&cur[wv >> 17], 1);
    csr[p] = (int)(wv & 0x1FFFFu);
  }
}

// ---------------------------------------------------------------------------
// MFMA GEMMs: 64x128 output tile, BK=64, 4 waves; wave w owns rows w*16..+16.
// LDS 16B-chunk XOR swizzle: phys_chunk = chunk ^ (row & 7).
// ---------------------------------------------------------------------------

// t0b[n,128](bf16) = (x[n,256] @ W0) * c_src[row]   (fp32 accum via MFMA)
__global__ __launch_bounds__(256) void gemm256_mfma(const float* __restrict__ x,
                                                    const ushort* __restrict__ W0t,
                                                    const float* __restrict__ c_src,
                                                    ushort* __restrict__ t0b, int n) {
  __shared__ alignas(16) ushort As[64 * 64];    // 8 KB
  __shared__ alignas(16) ushort Bs[128 * 64];   // 16 KB
  int tid = threadIdx.x;
  int row0 = blockIdx.x * 64;
  int lane = tid & 63;
  int w = tid >> 6;
  int l16 = lane & 15, hi = lane >> 4;
  f32x4 acc[8];
#pragma unroll
  for (int c = 0; c < 8; c++) acc[c] = (f32x4){0.f, 0.f, 0.f, 0.f};

  for (int kt = 0; kt < 256; kt += 64) {
    {  // stage A: row r=tid>>2, two 16B chunks; 8 fp32 -> 8 bf16 each
      int r = tid >> 2;
      int gr = row0 + r;
#pragma unroll
      for (int u = 0; u < 2; u++) {
        int c8 = (tid & 3) * 2 + u;  // 0..7
        float4 v0 = make_float4(0.f, 0.f, 0.f, 0.f), v1 = v0;
        if (gr < n) {
          v0 = ld4(&x[(size_t)gr * 256 + kt + c8 * 8]);
          v1 = ld4(&x[(size_t)gr * 256 + kt + c8 * 8 + 4]);
        }
        uint4 o;
        o.x = f2bf(v0.x) | (f2bf(v0.y) << 16);
        o.y = f2bf(v0.z) | (f2bf(v0.w) << 16);
        o.z = f2bf(v1.x) | (f2bf(v1.y) << 16);
        o.w = f2bf(v1.z) | (f2bf(v1.w) << 16);
        *(uint4*)&As[r * 64 + (c8 ^ (r & 7)) * 8] = o;
      }
    }
    {  // stage B: row r=tid>>1 (0..127), four 16B chunks from W0t (bf16)
      int r = tid >> 1;
#pragma unroll
      for (int u = 0; u < 4; u++) {
        int c8 = (tid & 1) * 4 + u;  // 0..7
        uint4 o = *(const uint4*)&W0t[(size_t)r * 256 + kt + c8 * 8];
        *(uint4*)&Bs[r * 64 + (c8 ^ (r & 7)) * 8] = o;
      }
    }
    __syncthreads();
#pragma unroll
    for (int ks = 0; ks < 2; ks++) {
      int ar = w * 16 + l16;
      int ac = ks * 4 + hi;
      short8 a = *(const short8*)&As[ar * 64 + (ac ^ (ar & 7)) * 8];
#pragma unroll
      for (int c = 0; c < 8; c++) {
        int br = c * 16 + l16;
        short8 b = *(const short8*)&Bs[br * 64 + (ac ^ (br & 7)) * 8];
        acc[c] = __builtin_amdgcn_mfma_f32_16x16x32_bf16(a, b, acc[c], 0, 0, 0);
      }
    }
    __syncthreads();
  }
  // epilogue: scale rows by c_src, store bf16
  float cs[4];
#pragma unroll
  for (int r = 0; r < 4; r++) {
    int gm = row0 + w * 16 + hi * 4 + r;
    cs[r] = (gm < n) ? c_src[gm] : 0.f;
  }
#pragma unroll
  for (int c = 0; c < 8; c++)
#pragma unroll
    for (int r = 0; r < 4; r++) {
      int gm = row0 + w * 16 + hi * 4 + r;
      if (gm < n) t0b[(size_t)gm * 128 + c * 16 + l16] = (ushort)f2bf(acc[c][r] * cs[r]);
    }
}

// t1b[n,128](bf16) = (h1b[n,128](bf16) @ W1) * c_src[row]   (MFMA)
__global__ __launch_bounds__(256) void gemm128_mfma(const ushort* __restrict__ A,
                                                    const ushort* __restrict__ W1t,
                                                    const float* __restrict__ c_src,
                                                    ushort* __restrict__ Y, int n) {
  __shared__ alignas(16) ushort As[64 * 64];    // 8 KB
  __shared__ alignas(16) ushort Bs[128 * 64];   // 16 KB
  int tid = threadIdx.x;
  int row0 = blockIdx.x * 64;
  int lane = tid & 63;
  int w = tid >> 6;
  int l16 = lane & 15, hi = lane >> 4;
  f32x4 acc[8];
#pragma unroll
  for (int c = 0; c < 8; c++) acc[c] = (f32x4){0.f, 0.f, 0.f, 0.f};

  for (int kt = 0; kt < 128; kt += 64) {
    {  // stage A (already bf16): row r=tid>>2, two 16B chunks
      int r = tid >> 2;
      int gr = row0 + r;
#pragma unroll
      for (int u = 0; u < 2; u++) {
        int c8 = (tid & 3) * 2 + u;
        uint4 o = make_uint4(0u, 0u, 0u, 0u);
        if (gr < n) o = *(const uint4*)&A[(size_t)gr * 128 + kt + c8 * 8];
        *(uint4*)&As[r * 64 + (c8 ^ (r & 7)) * 8] = o;
      }
    }
    {  // stage B from W1t
      int r = tid >> 1;
#pragma unroll
      for (int u = 0; u < 4; u++) {
        int c8 = (tid & 1) * 4 + u;
        uint4 o = *(const uint4*)&W1t[(size_t)r * 128 + kt + c8 * 8];
        *(uint4*)&Bs[r * 64 + (c8 ^ (r & 7)) * 8] = o;
      }
    }
    __syncthreads();
#pragma unroll
    for (int ks = 0; ks < 2; ks++) {
      int ar = w * 16 + l16;
      int ac = ks * 4 + hi;
      short8 a = *(const short8*)&As[ar * 64 + (ac ^ (ar & 7)) * 8];
#pragma unroll
      for (int c = 0; c < 8; c++) {
        int br = c * 16 + l16;
        short8 b = *(const short8*)&Bs[br * 64 + (ac ^ (br & 7)) * 8];
        acc[c] = __builtin_amdgcn_mfma_f32_16x16x32_bf16(a, b, acc[c], 0, 0, 0);
      }
    }
    __syncthreads();
  }
  float cs[4];
#pragma unroll
  for (int r = 0; r < 4; r++) {
    int gm = row0 + w * 16 + hi * 4 + r;
    cs[r] = (gm < n) ? c_src[gm] : 0.f;
  }
#pragma unroll
  for (int c = 0; c < 8; c++)
#pragma unroll
    for (int r = 0; r < 4; r++) {
      int gm = row0 + w * 16 + hi * 4 + r;
      if (gm < n) Y[(size_t)gm * 128 + c * 16 + l16] = (ushort)f2bf(acc[c][r] * cs[r]);
    }
}

// ---------------------------------------------------------------------------
// Persistent-wave aggregation (R8 structure): wave cooperatively loads 64
// edge indices in one coalesced read, broadcasts via __shfl, gathers 8-deep.
// T rows pre-scaled by c_src.
// ---------------------------------------------------------------------------
template <bool RELU, bool OUT_BF16>
__global__ __launch_bounds__(256) void agg_kernel(const ushort* __restrict__ T,
                                                  const int* __restrict__ row_start,
                                                  const int* __restrict__ csr_src,
                                                  const float* __restrict__ bias,
                                                  void* __restrict__ out, int n) {
  int lane = threadIdx.x & 63;
  int gw = (blockIdx.x * 256 + threadIdx.x) >> 6;
  int nw = gridDim.x * 4;
  float bx = bias[lane * 2], by = bias[lane * 2 + 1];
  for (int node = gw; node < n; node += nw) {
    int e0 = row_start[node], e1 = row_start[node + 1];
    float ax = 0.f, ay = 0.f;
    for (int eb = e0; eb < e1; eb += 64) {
      int rem = e1 - eb;
      int cnt = rem < 64 ? rem : 64;
      int msrc = (lane < rem) ? csr_src[eb + lane] : 0;
      int j = 0;
      for (; j + 7 < cnt; j += 8) {
        unsigned int w[8];
#pragma unroll
        for (int u = 0; u < 8; u++) {
          int s = __shfl(msrc, j + u);
          w[u] = *(const unsigned int*)&T[(size_t)s * 128 + lane * 2];
        }
#pragma unroll
        for (int u = 0; u < 8; u++) {
          ax += bf2f(w[u] & 0xffff);
          ay += bf2f(w[u] >> 16);
        }
      }
      for (; j + 1 < cnt; j += 2) {
        int s0 = __shfl(msrc, j), s1 = __shfl(msrc, j + 1);
        unsigned int w0 = *(const unsigned int*)&T[(size_t)s0 * 128 + lane * 2];
        unsigned int w1 = *(const unsigned int*)&T[(size_t)s1 * 128 + lane * 2];
        ax += bf2f(w0 & 0xffff) + bf2f(w1 & 0xffff);
        ay += bf2f(w0 >> 16) + bf2f(w1 >> 16);
      }
      if (j < cnt) {
        int s0 = __shfl(msrc, j);
        unsigned int w0 = *(const unsigned int*)&T[(size_t)s0 * 128 + lane * 2];
        ax += bf2f(w0 & 0xffff);
        ay += bf2f(w0 >> 16);
      }
    }
    float cd = rsqrtf(fmaxf((float)(e1 - e0), 1.0f));
    float rx = fmaf(ax, cd, bx);
    float ry = fmaf(ay, cd, by);
    if (RELU) { rx = fmaxf(rx, 0.f); ry = fmaxf(ry, 0.f); }
    if (OUT_BF16) {
      ((unsigned int*)out)[(size_t)node * 64 + lane] = f2bf(rx) | (f2bf(ry) << 16);
    } else {
      float2 r2; r2.x = rx; r2.y = ry;
      ((float2*)out)[(size_t)node * 64 + lane] = r2;
    }
  }
}

// logits[n,40] = relu(H[n,128]) @ Wc[128,40] + bc
__global__ __launch_bounds__(256) void logits_kernel(const float* __restrict__ H,
                                                     const float* __restrict__ Wc,
                                                     const float* __restrict__ bc,
                                                     float* __restrict__ out, int n) {
  __shared__ float Wl[128 * 40];
  for (int i = threadIdx.x; i < 128 * 40; i += 256) Wl[i] = Wc[i];
  __syncthreads();
  int rl = threadIdx.x >> 3;
  int cg = threadIdx.x & 7;
  int r = blockIdx.x * 32 + rl;
  if (r >= n) return;
  float acc[5] = {0.f, 0.f, 0.f, 0.f, 0.f};
  const float* hr = &H[(size_t)r * 128];
  for (int k = 0; k < 128; k++) {
    float v = fmaxf(hr[k], 0.f);
#pragma unroll
    for (int j = 0; j < 5; j++) acc[j] = fmaf(v, Wl[k * 40 + cg * 5 + j], acc[j]);
  }
#pragma unroll
  for (int j = 0; j < 5; j++) out[(size_t)r * 40 + cg * 5 + j] = acc[j] + bc[cg * 5 + j];
}

extern "C" void kernel_launch(void* const* d_in, const int* in_sizes, int n_in,
                              void* d_out, int out_size, void* d_ws, size_t ws_size,
                              hipStream_t stream) {
  const float* x = (const float*)d_in[0];
  const int* src = (const int*)d_in[1];
  const int* dst = (const int*)d_in[2];
  const float* W0 = (const float*)d_in[3];
  const float* b0 = (const float*)d_in[4];
  const float* W1 = (const float*)d_in[5];
  const float* b1 = (const float*)d_in[6];
  const float* Wc = (const float*)d_in[7];
  const float* bc = (const float*)d_in[8];
  const int n = in_sizes[0] / 256;
  const int E = in_sizes[1];
  const int nbk = (n + NPB - 1) >> BSHIFT;          // 782 (<=1024)
  const int nblk = (E + CHUNK - 1) / CHUNK;         // 250 (<=256)

  char* wsp = (char*)d_ws;
  auto alloc = [&](size_t bytes) -> char* {
    char* p = wsp;
    wsp += (bytes + 255) & ~(size_t)255;
    return p;
  };
  ushort* t0b = (ushort*)alloc((size_t)n * 128 * sizeof(ushort));  // t0 / reused as t1
  ushort* h1b = (ushort*)alloc((size_t)n * 128 * sizeof(ushort));
  float* c_src = (float*)alloc((size_t)n * sizeof(float));
  ushort* W0t = (ushort*)alloc((size_t)128 * 256 * sizeof(ushort));
  ushort* W1t = (ushort*)alloc((size_t)128 * 128 * sizeof(ushort));
  int* bhD = (int*)alloc((size_t)nblk * nbk * sizeof(int));
  int* bhS = (int*)alloc((size_t)nblk * nbk * sizeof(int));
  int* totD = (int*)alloc((size_t)nbk * sizeof(int));
  int* totS = (int*)alloc((size_t)nbk * sizeof(int));
  int* baseD = (int*)alloc((size_t)(nbk + 1) * sizeof(int));
  int* baseS = (int*)alloc((size_t)(nbk + 1) * sizeof(int));
  unsigned int* ebufD = (unsigned int*)alloc((size_t)E * sizeof(unsigned int));
  uint8_t* ebufS = (uint8_t*)alloc((size_t)E);
  int* row_start = (int*)alloc((size_t)(n + 1) * sizeof(int));
  int* csr = (int*)alloc((size_t)E * sizeof(int));

  float* h_out = (float*)d_out;             // n x 128 (h2)
  float* logits = h_out + (size_t)n * 128;  // n x 40

  // 1) weight transpose+cast
  prep_weights<<<128, 256, 0, stream>>>(W0, W1, W0t, W1t);
  // 2) CSR build: hist -> scans -> LDS-sorted scatter -> per-bucket fill
  bucket_hist<<<nblk, 256, 0, stream>>>(src, dst, bhD, bhS, E, nbk);
  bucket_scan_blocks<<<nbk, 256, 0, stream>>>(bhD, bhS, totD, totS, nbk, nblk);
  bucket_base<<<1, 1024, 0, stream>>>(totD, totS, baseD, baseS, nbk);
  sort_scatter<<<nblk, 256, 0, stream>>>(src, dst, bhD, bhS, baseD, baseS,
                                         ebufD, ebufS, E, nbk);
  csr_outdeg<<<nbk, 256, 0, stream>>>(ebufD, ebufS, baseD, baseS,
                                      row_start, csr, c_src, n, nbk);
  // 3) t0b(bf16) = (x @ W0) * c_src[row]   (MFMA; c_src folded)
  gemm256_mfma<<<(n + 63) / 64, 256, 0, stream>>>(x, W0t, c_src, t0b, n);
  // 4) h1b(bf16) = relu(agg(t0b) * c_dst + b0)
  agg_kernel<true, true><<<2048, 256, 0, stream>>>(
      t0b, row_start, csr, b0, (void*)h1b, n);
  // 5) t1b(bf16) = (h1b @ W1) * c_src   (reuse t0b buffer)
  gemm128_mfma<<<(n + 63) / 64, 256, 0, stream>>>(h1b, W1t, c_src, t0b, n);
  // 6) h2(fp32, d_out) = agg(t1b) * c_dst + b1
  agg_kernel<false, false><<<2048, 256, 0, stream>>>(
      t0b, row_start, csr, b1, (void*)h_out, n);
  // 7) logits = relu(h2) @ Wc + bc
  logits_kernel<<<(n + 31) / 32, 256, 0, stream>>>(h_out, Wc, bc, logits, n);
}

// Round 8
// 451.860 us; speedup vs baseline: 1.2983x; 1.0337x over previous
//
#include <hip/hip_runtime.h>
#include <cstdint>
#include <cstddef>

// ---------------------------------------------------------------------------
// GCN forward on MI355X.
// R12: R11's cooperative fusion never executed (absmax = |ref| signature;
//      hipLaunchCooperativeKernel likely rejected under graph capture).
//      Back to the known-good R8 separate-launch structure + algebraic fusion:
//      segsum((h1*c_src)[src]) @ W1 == segsum(((h1@W1)*c_src)[src]) and
//      c_dst row-scaling commutes with @W1. So: agg1 emits h1s=relu(h1)*c_src
//      (bf16); agg2 aggregates h1s and emits gb=g*c_dst (bf16, half the
//      write); final_kernel does h2=gb@W1+b1 (MFMA) AND fused logits from
//      the on-chip h2 tile. Deletes gemm128's t1b round-trip and logits'
//      50MB h2 re-read. prep merged into hist. 11 -> 9 launches.
// ---------------------------------------------------------------------------

#define NPB 128        // nodes per bucket
#define BSHIFT 7
#define EPT3 25
#define CHUNK (EPT3 * 256)   // 6400 edges per build block

typedef __attribute__((ext_vector_type(8))) short short8;
typedef __attribute__((ext_vector_type(4))) float f32x4;

static __device__ __forceinline__ float4 ld4(const float* p) { return *(const float4*)p; }

static __device__ __forceinline__ float bf2f(unsigned int u) {
  union { unsigned int i; float f; } x; x.i = u << 16; return x.f;
}
static __device__ __forceinline__ unsigned int f2bf(float f) {
  union { float f; unsigned int i; } x; x.f = f;
  unsigned int r = x.i + 0x7fff + ((x.i >> 16) & 1);  // RTN-even
  return r >> 16;
}

// ---- K1: per-block bucket histograms (blocks < nblk) + weight prep --------
__global__ __launch_bounds__(256) void hist_prep(
    const int* __restrict__ src, const int* __restrict__ dst,
    const float* __restrict__ W0, const float* __restrict__ W1,
    ushort* __restrict__ W0t, ushort* __restrict__ W1t,
    int* __restrict__ bhD, int* __restrict__ bhS, int E, int nbk, int nblk) {
  __shared__ int hD[1024], hS[1024];
  int bid = blockIdx.x, t = threadIdx.x;
  if (bid >= nblk) {  // weight transpose+cast role (128 blocks)
    int idx = (bid - nblk) * 256 + t;
    if (idx < 128 * 256) {
      int nn = idx >> 8, kk = idx & 255;
      W0t[nn * 256 + kk] = (ushort)f2bf(W0[kk * 128 + nn]);
    }
    if (idx < 128 * 128) {
      int nn = idx >> 7, kk = idx & 127;
      W1t[nn * 128 + kk] = (ushort)f2bf(W1[kk * 128 + nn]);
    }
    return;
  }
  for (int i = t; i < nbk; i += 256) { hD[i] = 0; hS[i] = 0; }
  __syncthreads();
  int base = bid * CHUNK + t;
  for (int j = 0; j < EPT3; j++) {
    int e = base + j * 256;
    if (e < E) {
      atomicAdd(&hD[dst[e] >> BSHIFT], 1);
      atomicAdd(&hS[src[e] >> BSHIFT], 1);
    }
  }
  __syncthreads();
  for (int i = t; i < nbk; i += 256) {
    bhD[(size_t)bid * nbk + i] = hD[i];
    bhS[(size_t)bid * nbk + i] = hS[i];
  }
}

// ---- K2a: per-bucket exclusive scan across the nblk edge-blocks -----------
__global__ __launch_bounds__(256) void bucket_scan_blocks(int* __restrict__ bhD,
                                                          int* __restrict__ bhS,
                                                          int* __restrict__ totD,
                                                          int* __restrict__ totS,
                                                          int nbk, int nblk) {
  __shared__ int lds[256];
  int b = blockIdx.x, t = threadIdx.x;
  int v = (t < nblk) ? bhD[(size_t)t * nbk + b] : 0;
  lds[t] = v;
  __syncthreads();
  for (int off = 1; off < 256; off <<= 1) {
    int u = (t >= off) ? lds[t - off] : 0;
    __syncthreads();
    lds[t] += u;
    __syncthreads();
  }
  if (t < nblk) bhD[(size_t)t * nbk + b] = lds[t] - v;  // exclusive
  if (t == 255) totD[b] = lds[255];
  __syncthreads();
  int w = (t < nblk) ? bhS[(size_t)t * nbk + b] : 0;
  lds[t] = w;
  __syncthreads();
  for (int off = 1; off < 256; off <<= 1) {
    int u = (t >= off) ? lds[t - off] : 0;
    __syncthreads();
    lds[t] += u;
    __syncthreads();
  }
  if (t < nblk) bhS[(size_t)t * nbk + b] = lds[t] - w;
  if (t == 255) totS[b] = lds[255];
}

// ---- K2b: exclusive scan over bucket totals (nbk <= 1024) -----------------
__global__ __launch_bounds__(1024) void bucket_base(const int* __restrict__ totD,
                                                    const int* __restrict__ totS,
                                                    int* __restrict__ baseD,
                                                    int* __restrict__ baseS, int nbk) {
  __shared__ int lds[1024];
  int t = threadIdx.x;
  int v = (t < nbk) ? totD[t] : 0;
  lds[t] = v;
  __syncthreads();
  for (int off = 1; off < 1024; off <<= 1) {
    int u = (t >= off) ? lds[t - off] : 0;
    __syncthreads();
    lds[t] += u;
    __syncthreads();
  }
  if (t < nbk) baseD[t] = lds[t] - v;
  if (t == 1023) baseD[nbk] = lds[1023];
  __syncthreads();
  int w = (t < nbk) ? totS[t] : 0;
  lds[t] = w;
  __syncthreads();
  for (int off = 1; off < 1024; off <<= 1) {
    int u = (t >= off) ? lds[t - off] : 0;
    __syncthreads();
    lds[t] += u;
    __syncthreads();
  }
  if (t < nbk) baseS[t] = lds[t] - w;
  if (t == 1023) baseS[nbk] = lds[1023];
}

// ---- K3: scatter edges into bucket segments (LDS cursors) -----------------
// ebufD word: bits[23:17]=dst&127, bits[16:0]=src   (n < 2^17)
__global__ __launch_bounds__(256) void bucket_scatter(
    const int* __restrict__ src, const int* __restrict__ dst,
    const int* __restrict__ bhD, const int* __restrict__ bhS,
    const int* __restrict__ baseD, const int* __restrict__ baseS,
    unsigned int* __restrict__ ebufD, uint8_t* __restrict__ ebufS,
    int E, int nbk) {
  __shared__ int cD[1024], cS[1024];
  int k = blockIdx.x, t = threadIdx.x;
  for (int i = t; i < nbk; i += 256) {
    cD[i] = baseD[i] + bhD[(size_t)k * nbk + i];
    cS[i] = baseS[i] + bhS[(size_t)k * nbk + i];
  }
  __syncthreads();
  int base = k * CHUNK + t;
  for (int j = 0; j < EPT3; j++) {
    int e = base + j * 256;
    if (e < E) {
      int s = src[e], d = dst[e];
      int pD = atomicAdd(&cD[d >> BSHIFT], 1);
      ebufD[pD] = ((unsigned int)(d & (NPB - 1)) << 17) | (unsigned int)s;
      int pS = atomicAdd(&cS[s >> BSHIFT], 1);
      ebufS[pS] = (uint8_t)(s & (NPB - 1));
    }
  }
}

// ---- K4: per dst-bucket csr fill + row_start + outdeg/c_src ---------------
__global__ __launch_bounds__(256) void csr_outdeg(
    const unsigned int* __restrict__ ebufD, const uint8_t* __restrict__ ebufS,
    const int* __restrict__ baseD, const int* __restrict__ baseS,
    int* __restrict__ row_start, int* __restrict__ csr,
    float* __restrict__ c_src, int n, int nbk) {
  __shared__ int cnt[NPB], sc[NPB], cur[NPB], cntS[NPB];
  int b = blockIdx.x, t = threadIdx.x;
  if (t < NPB) { cnt[t] = 0; cntS[t] = 0; }
  __syncthreads();
  int s0 = baseD[b], s1 = baseD[b + 1];
  for (int i = s0 + t; i < s1; i += 256) atomicAdd(&cnt[ebufD[i] >> 17], 1);
  int u0 = baseS[b], u1 = baseS[b + 1];
  for (int i = u0 + t; i < u1; i += 256) atomicAdd(&cntS[ebufS[i]], 1);
  __syncthreads();
  int c = (t < NPB) ? cnt[t] : 0;
  if (t < NPB) sc[t] = c;
  __syncthreads();
  for (int off = 1; off < NPB; off <<= 1) {
    int u = (t < NPB && t >= off) ? sc[t - off] : 0;
    __syncthreads();
    if (t < NPB) sc[t] += u;
    __syncthreads();
  }
  if (t < NPB) {
    int start = s0 + sc[t] - c;  // exclusive
    cur[t] = start;
    int node = b * NPB + t;
    if (node < n) {
      row_start[node] = start;
      c_src[node] = rsqrtf(fmaxf((float)cntS[t], 1.0f));
    }
  }
  if (b == 0 && t == 0) row_start[n] = baseD[nbk];
  __syncthreads();
  for (int i = s0 + t; i < s1; i += 256) {
    unsigned int wv = ebufD[i];
    int p = atomicAdd(&cur[wv >> 17], 1);
    csr[p] = (int)(wv & 0x1FFFFu);
  }
}

// ---------------------------------------------------------------------------
// MFMA gemm256: 64x128 tile, BK=64, 4 waves, XOR-swizzled LDS (16B chunk
// ^ row&7).  t0b[n,128](bf16) = (x[n,256] @ W0) * c_src[row].
// ---------------------------------------------------------------------------
__global__ __launch_bounds__(256) void gemm256_mfma(const float* __restrict__ x,
                                                    const ushort* __restrict__ W0t,
                                                    const float* __restrict__ c_src,
                                                    ushort* __restrict__ t0b, int n) {
  __shared__ alignas(16) ushort As[64 * 64];    // 8 KB
  __shared__ alignas(16) ushort Bs[128 * 64];   // 16 KB
  int tid = threadIdx.x;
  int row0 = blockIdx.x * 64;
  int lane = tid & 63;
  int w = tid >> 6;
  int l16 = lane & 15, hi = lane >> 4;
  f32x4 acc[8];
#pragma unroll
  for (int c = 0; c < 8; c++) acc[c] = (f32x4){0.f, 0.f, 0.f, 0.f};

  for (int kt = 0; kt < 256; kt += 64) {
    {  // stage A: row r=tid>>2, two 16B chunks; 8 fp32 -> 8 bf16 each
      int r = tid >> 2;
      int gr = row0 + r;
#pragma unroll
      for (int u = 0; u < 2; u++) {
        int c8 = (tid & 3) * 2 + u;  // 0..7
        float4 v0 = make_float4(0.f, 0.f, 0.f, 0.f), v1 = v0;
        if (gr < n) {
          v0 = ld4(&x[(size_t)gr * 256 + kt + c8 * 8]);
          v1 = ld4(&x[(size_t)gr * 256 + kt + c8 * 8 + 4]);
        }
        uint4 o;
        o.x = f2bf(v0.x) | (f2bf(v0.y) << 16);
        o.y = f2bf(v0.z) | (f2bf(v0.w) << 16);
        o.z = f2bf(v1.x) | (f2bf(v1.y) << 16);
        o.w = f2bf(v1.z) | (f2bf(v1.w) << 16);
        *(uint4*)&As[r * 64 + (c8 ^ (r & 7)) * 8] = o;
      }
    }
    {  // stage B: row r=tid>>1 (0..127), four 16B chunks from W0t (bf16)
      int r = tid >> 1;
#pragma unroll
      for (int u = 0; u < 4; u++) {
        int c8 = (tid & 1) * 4 + u;  // 0..7
        uint4 o = *(const uint4*)&W0t[(size_t)r * 256 + kt + c8 * 8];
        *(uint4*)&Bs[r * 64 + (c8 ^ (r & 7)) * 8] = o;
      }
    }
    __syncthreads();
#pragma unroll
    for (int ks = 0; ks < 2; ks++) {
      int ar = w * 16 + l16;
      int ac = ks * 4 + hi;
      short8 a = *(const short8*)&As[ar * 64 + (ac ^ (ar & 7)) * 8];
#pragma unroll
      for (int c = 0; c < 8; c++) {
        int br = c * 16 + l16;
        short8 b = *(const short8*)&Bs[br * 64 + (ac ^ (br & 7)) * 8];
        acc[c] = __builtin_amdgcn_mfma_f32_16x16x32_bf16(a, b, acc[c], 0, 0, 0);
      }
    }
    __syncthreads();
  }
  float cs[4];
#pragma unroll
  for (int r = 0; r < 4; r++) {
    int gm = row0 + w * 16 + hi * 4 + r;
    cs[r] = (gm < n) ? c_src[gm] : 0.f;
  }
#pragma unroll
  for (int c = 0; c < 8; c++)
#pragma unroll
    for (int r = 0; r < 4; r++) {
      int gm = row0 + w * 16 + hi * 4 + r;
      if (gm < n) t0b[(size_t)gm * 128 + c * 16 + l16] = (ushort)f2bf(acc[c][r] * cs[r]);
    }
}

// ---------------------------------------------------------------------------
// Persistent-wave aggregation (R8 gather structure).
// MODE 0 (layer 1): out = (relu(agg*cd + b0)) * c_src[node]   (bf16)
// MODE 1 (layer 2): out = agg * cd                            (bf16, no bias)
// ---------------------------------------------------------------------------
template <int MODE>
__global__ __launch_bounds__(256) void agg_kernel(const ushort* __restrict__ T,
                                                  const int* __restrict__ row_start,
                                                  const int* __restrict__ csr_src,
                                                  const float* __restrict__ c_src,
                                                  const float* __restrict__ bias,
                                                  unsigned int* __restrict__ out, int n) {
  int lane = threadIdx.x & 63;
  int gw = (blockIdx.x * 256 + threadIdx.x) >> 6;
  int nw = gridDim.x * 4;
  float bx = 0.f, by = 0.f;
  if (MODE == 0) { bx = bias[lane * 2]; by = bias[lane * 2 + 1]; }
  for (int node = gw; node < n; node += nw) {
    int e0 = row_start[node], e1 = row_start[node + 1];
    float ax = 0.f, ay = 0.f;
    for (int eb = e0; eb < e1; eb += 64) {
      int rem = e1 - eb;
      int cnt = rem < 64 ? rem : 64;
      int msrc = (lane < rem) ? csr_src[eb + lane] : 0;
      int j = 0;
      for (; j + 7 < cnt; j += 8) {
        unsigned int w[8];
#pragma unroll
        for (int u = 0; u < 8; u++) {
          int s = __shfl(msrc, j + u);
          w[u] = *(const unsigned int*)&T[(size_t)s * 128 + lane * 2];
        }
#pragma unroll
        for (int u = 0; u < 8; u++) {
          ax += bf2f(w[u] & 0xffff);
          ay += bf2f(w[u] >> 16);
        }
      }
      for (; j + 1 < cnt; j += 2) {
        int s0 = __shfl(msrc, j), s1 = __shfl(msrc, j + 1);
        unsigned int w0 = *(const unsigned int*)&T[(size_t)s0 * 128 + lane * 2];
        unsigned int w1 = *(const unsigned int*)&T[(size_t)s1 * 128 + lane * 2];
        ax += bf2f(w0 & 0xffff) + bf2f(w1 & 0xffff);
        ay += bf2f(w0 >> 16) + bf2f(w1 >> 16);
      }
      if (j < cnt) {
        int s0 = __shfl(msrc, j);
        unsigned int w0 = *(const unsigned int*)&T[(size_t)s0 * 128 + lane * 2];
        ax += bf2f(w0 & 0xffff);
        ay += bf2f(w0 >> 16);
      }
    }
    float cd = rsqrtf(fmaxf((float)(e1 - e0), 1.0f));
    float rx, ry;
    if (MODE == 0) {
      float csn = c_src[node];
      rx = fmaxf(fmaf(ax, cd, bx), 0.f) * csn;
      ry = fmaxf(fmaf(ay, cd, by), 0.f) * csn;
    } else {
      rx = ax * cd;
      ry = ay * cd;
    }
    out[(size_t)node * 64 + lane] = f2bf(rx) | (f2bf(ry) << 16);
  }
}

// ---------------------------------------------------------------------------
// final: h2[n,128](fp32,d_out) = gb[n,128](bf16) @ W1 + b1   (MFMA)
//        logits[n,40] = relu(h2) @ Wc + bc  -- fused from the on-chip tile.
// ---------------------------------------------------------------------------
#define HSTRIDE 130   // pad so Hs rows land in distinct banks
__global__ __launch_bounds__(256) void final_kernel(const ushort* __restrict__ gb,
                                                    const ushort* __restrict__ W1t,
                                                    const float* __restrict__ b1,
                                                    const float* __restrict__ Wc,
                                                    const float* __restrict__ bc,
                                                    float* __restrict__ h_out,
                                                    float* __restrict__ logits, int n) {
  __shared__ alignas(16) union {
    struct { ushort As[64 * 64]; ushort Bs[128 * 64]; } g;  // 24 KB (MFMA phase)
    float Wl[128 * 40];                                     // 20 KB (logits phase)
  } sm;
  __shared__ ushort Hs[64 * HSTRIDE];                       // relu(h2) bf16, 16.6 KB
  int tid = threadIdx.x;
  int row0 = blockIdx.x * 64;
  int lane = tid & 63;
  int w = tid >> 6;
  int l16 = lane & 15, hi = lane >> 4;
  f32x4 acc[8];
#pragma unroll
  for (int c = 0; c < 8; c++) acc[c] = (f32x4){0.f, 0.f, 0.f, 0.f};

  for (int kt = 0; kt < 128; kt += 64) {
    {  // stage A from gb (bf16)
      int r = tid >> 2;
      int gr = row0 + r;
#pragma unroll
      for (int u = 0; u < 2; u++) {
        int c8 = (tid & 3) * 2 + u;
        uint4 o = make_uint4(0u, 0u, 0u, 0u);
        if (gr < n) o = *(const uint4*)&gb[(size_t)gr * 128 + kt + c8 * 8];
        *(uint4*)&sm.g.As[r * 64 + (c8 ^ (r & 7)) * 8] = o;
      }
    }
    {  // stage B from W1t
      int r = tid >> 1;
#pragma unroll
      for (int u = 0; u < 4; u++) {
        int c8 = (tid & 1) * 4 + u;
        uint4 o = *(const uint4*)&W1t[(size_t)r * 128 + kt + c8 * 8];
        *(uint4*)&sm.g.Bs[r * 64 + (c8 ^ (r & 7)) * 8] = o;
      }
    }
    __syncthreads();
#pragma unroll
    for (int ks = 0; ks < 2; ks++) {
      int ar = w * 16 + l16;
      int ac = ks * 4 + hi;
      short8 a = *(const short8*)&sm.g.As[ar * 64 + (ac ^ (ar & 7)) * 8];
#pragma unroll
      for (int c = 0; c < 8; c++) {
        int br = c * 16 + l16;
        short8 b = *(const short8*)&sm.g.Bs[br * 64 + (ac ^ (br & 7)) * 8];
        acc[c] = __builtin_amdgcn_mfma_f32_16x16x32_bf16(a, b, acc[c], 0, 0, 0);
      }
    }
    __syncthreads();
  }
  // epilogue: h2 = acc + b1 -> d_out (fp32); relu(h2) bf16 -> Hs
#pragma unroll
  for (int c = 0; c < 8; c++) {
    int col = c * 16 + l16;
    float bb = b1[col];
#pragma unroll
    for (int r = 0; r < 4; r++) {
      int rl = w * 16 + hi * 4 + r;
      int gm = row0 + rl;
      float h2 = acc[c][r] + bb;
      if (gm < n) h_out[(size_t)gm * 128 + col] = h2;
      Hs[rl * HSTRIDE + col] = (ushort)f2bf(fmaxf(h2, 0.f));
    }
  }
  __syncthreads();
  for (int i = tid; i < 128 * 40; i += 256) sm.Wl[i] = Wc[i];
  __syncthreads();
  // logits: 2 passes x 32 rows; 8 threads/row, 5 outputs each
  int cg = tid & 7;
#pragma unroll
  for (int pass = 0; pass < 2; pass++) {
    int rl = pass * 32 + (tid >> 3);
    int gm = row0 + rl;
    if (gm < n) {
      float a5[5] = {0.f, 0.f, 0.f, 0.f, 0.f};
      for (int k = 0; k < 128; k++) {
        float v = bf2f(Hs[rl * HSTRIDE + k]);
#pragma unroll
        for (int j = 0; j < 5; j++) a5[j] = fmaf(v, sm.Wl[k * 40 + cg * 5 + j], a5[j]);
      }
#pragma unroll
      for (int j = 0; j < 5; j++)
        logits[(size_t)gm * 40 + cg * 5 + j] = a5[j] + bc[cg * 5 + j];
    }
  }
}

extern "C" void kernel_launch(void* const* d_in, const int* in_sizes, int n_in,
                              void* d_out, int out_size, void* d_ws, size_t ws_size,
                              hipStream_t stream) {
  const float* x = (const float*)d_in[0];
  const int* src = (const int*)d_in[1];
  const int* dst = (const int*)d_in[2];
  const float* W0 = (const float*)d_in[3];
  const float* b0 = (const float*)d_in[4];
  const float* W1 = (const float*)d_in[5];
  const float* b1 = (const float*)d_in[6];
  const float* Wc = (const float*)d_in[7];
  const float* bc = (const float*)d_in[8];
  const int n = in_sizes[0] / 256;
  const int E = in_sizes[1];
  const int nbk = (n + NPB - 1) >> BSHIFT;          // 782 (<=1024)
  const int nblk = (E + CHUNK - 1) / CHUNK;         // 250 (<=256)

  char* wsp = (char*)d_ws;
  auto alloc = [&](size_t bytes) -> char* {
    char* p = wsp;
    wsp += (bytes + 255) & ~(size_t)255;
    return p;
  };
  ushort* t0b = (ushort*)alloc((size_t)n * 128 * sizeof(ushort));  // t0 / reused as gb
  ushort* h1s = (ushort*)alloc((size_t)n * 128 * sizeof(ushort));
  float* c_src = (float*)alloc((size_t)n * sizeof(float));
  ushort* W0t = (ushort*)alloc((size_t)128 * 256 * sizeof(ushort));
  ushort* W1t = (ushort*)alloc((size_t)128 * 128 * sizeof(ushort));
  int* bhD = (int*)alloc((size_t)nblk * nbk * sizeof(int));
  int* bhS = (int*)alloc((size_t)nblk * nbk * sizeof(int));
  int* totD = (int*)alloc((size_t)nbk * sizeof(int));
  int* totS = (int*)alloc((size_t)nbk * sizeof(int));
  int* baseD = (int*)alloc((size_t)(nbk + 1) * sizeof(int));
  int* baseS = (int*)alloc((size_t)(nbk + 1) * sizeof(int));
  unsigned int* ebufD = (unsigned int*)alloc((size_t)E * sizeof(unsigned int));
  uint8_t* ebufS = (uint8_t*)alloc((size_t)E);
  int* row_start = (int*)alloc((size_t)(n + 1) * sizeof(int));
  int* csr = (int*)alloc((size_t)E * sizeof(int));

  float* h_out = (float*)d_out;             // n x 128 (h2)
  float* logits = h_out + (size_t)n * 128;  // n x 40

  // 1) hist (blocks 0..nblk) + weight prep (blocks nblk..nblk+128)
  hist_prep<<<nblk + 128, 256, 0, stream>>>(src, dst, W0, W1, W0t, W1t,
                                            bhD, bhS, E, nbk, nblk);
  // 2-5) CSR build
  bucket_scan_blocks<<<nbk, 256, 0, stream>>>(bhD, bhS, totD, totS, nbk, nblk);
  bucket_base<<<1, 1024, 0, stream>>>(totD, totS, baseD, baseS, nbk);
  bucket_scatter<<<nblk, 256, 0, stream>>>(src, dst, bhD, bhS, baseD, baseS,
                                           ebufD, ebufS, E, nbk);
  csr_outdeg<<<nbk, 256, 0, stream>>>(ebufD, ebufS, baseD, baseS,
                                      row_start, csr, c_src, n, nbk);
  // 6) t0b(bf16) = (x @ W0) * c_src[row]
  gemm256_mfma<<<(n + 63) / 64, 256, 0, stream>>>(x, W0t, c_src, t0b, n);
  // 7) h1s(bf16) = relu(agg(t0b) * cd + b0) * c_src[node]
  agg_kernel<0><<<2048, 256, 0, stream>>>(t0b, row_start, csr, c_src, b0,
                                          (unsigned int*)h1s, n);
  // 8) gb(bf16, reuse t0b) = agg(h1s) * cd
  agg_kernel<1><<<2048, 256, 0, stream>>>(h1s, row_start, csr, c_src, b1,
                                          (unsigned int*)t0b, n);
  // 9) h2(fp32,d_out) = gb @ W1 + b1 ; logits = relu(h2) @ Wc + bc (fused)
  final_kernel<<<(n + 63) / 64, 256, 0, stream>>>(t0b, W1t, b1, Wc, bc,
                                                  h_out, logits, n);
}

// Round 9
// 446.706 us; speedup vs baseline: 1.3133x; 1.0115x over previous
//
#include <hip/hip_runtime.h>
#include <cstdint>
#include <cstddef>

// ---------------------------------------------------------------------------
// GCN forward on MI355X.
// R13: two structural deletions on top of R12 (451.9us).
//  (1) agg2+final fused into agg_final: layer-2 aggregation result IS the
//      A-operand of the h2=gb@W1 MFMA -> aggregate straight into LDS in
//      MFMA A-layout (swizzled), then MFMA + fused logits in-block. Deletes
//      the gb 25MB write + 25.6MB read and one launch. 512 thr/block,
//      LDS phases unioned (As/Bs 32KB <-> Hs+Wl 36.6KB) -> 3-4 blocks/CU.
//  (2) bucket_base deleted: scatter & csr_outdeg recompute the 782-entry
//      exclusive bucket-base scan redundantly in LDS from totD/totS
//      (deterministic, parallel, ~3us); row_start[n] = E.
//  Top-5 also exposed the harness's 61us/iter workspace re-poison fill
//  (400MB @ 84% HBM) -- fixed cost, not addressable from kernel side.
// ---------------------------------------------------------------------------

#define NPB 128        // nodes per bucket
#define BSHIFT 7
#define EPT3 25
#define CHUNK (EPT3 * 256)   // 6400 edges per build block

typedef __attribute__((ext_vector_type(8))) short short8;
typedef __attribute__((ext_vector_type(4))) float f32x4;

static __device__ __forceinline__ float4 ld4(const float* p) { return *(const float4*)p; }

static __device__ __forceinline__ float bf2f(unsigned int u) {
  union { unsigned int i; float f; } x; x.i = u << 16; return x.f;
}
static __device__ __forceinline__ unsigned int f2bf(float f) {
  union { float f; unsigned int i; } x; x.f = f;
  unsigned int r = x.i + 0x7fff + ((x.i >> 16) & 1);  // RTN-even
  return r >> 16;
}

// exclusive scan of g[0..nbk) (nbk<=1024) into LDS arr[0..1024); 256 threads.
static __device__ __forceinline__ void excl_scan(const int* __restrict__ g,
                                                 int* arr, int* scanT, int nbk) {
  int t = threadIdx.x;
  int v[4]; int s = 0;
#pragma unroll
  for (int j = 0; j < 4; j++) {
    int idx = t * 4 + j;
    v[j] = (idx < nbk) ? g[idx] : 0;
    s += v[j];
  }
  scanT[t] = s;
  __syncthreads();
  for (int off = 1; off < 256; off <<= 1) {
    int u = (t >= off) ? scanT[t - off] : 0;
    __syncthreads();
    scanT[t] += u;
    __syncthreads();
  }
  int run = scanT[t] - s;
#pragma unroll
  for (int j = 0; j < 4; j++) {
    arr[t * 4 + j] = run;
    run += v[j];
  }
  __syncthreads();
}

// ---- K1: per-block bucket histograms (blocks < nblk) + weight prep --------
__global__ __launch_bounds__(256) void hist_prep(
    const int* __restrict__ src, const int* __restrict__ dst,
    const float* __restrict__ W0, const float* __restrict__ W1,
    ushort* __restrict__ W0t, ushort* __restrict__ W1t,
    int* __restrict__ bhD, int* __restrict__ bhS, int E, int nbk, int nblk) {
  __shared__ int hD[1024], hS[1024];
  int bid = blockIdx.x, t = threadIdx.x;
  if (bid >= nblk) {  // weight transpose+cast role (128 blocks)
    int idx = (bid - nblk) * 256 + t;
    if (idx < 128 * 256) {
      int nn = idx >> 8, kk = idx & 255;
      W0t[nn * 256 + kk] = (ushort)f2bf(W0[kk * 128 + nn]);
    }
    if (idx < 128 * 128) {
      int nn = idx >> 7, kk = idx & 127;
      W1t[nn * 128 + kk] = (ushort)f2bf(W1[kk * 128 + nn]);
    }
    return;
  }
  for (int i = t; i < nbk; i += 256) { hD[i] = 0; hS[i] = 0; }
  __syncthreads();
  int base = bid * CHUNK + t;
  for (int j = 0; j < EPT3; j++) {
    int e = base + j * 256;
    if (e < E) {
      atomicAdd(&hD[dst[e] >> BSHIFT], 1);
      atomicAdd(&hS[src[e] >> BSHIFT], 1);
    }
  }
  __syncthreads();
  for (int i = t; i < nbk; i += 256) {
    bhD[(size_t)bid * nbk + i] = hD[i];
    bhS[(size_t)bid * nbk + i] = hS[i];
  }
}

// ---- K2: per-bucket exclusive scan across the nblk edge-blocks ------------
__global__ __launch_bounds__(256) void bucket_scan_blocks(int* __restrict__ bhD,
                                                          int* __restrict__ bhS,
                                                          int* __restrict__ totD,
                                                          int* __restrict__ totS,
                                                          int nbk, int nblk) {
  __shared__ int lds[256];
  int b = blockIdx.x, t = threadIdx.x;
  int v = (t < nblk) ? bhD[(size_t)t * nbk + b] : 0;
  lds[t] = v;
  __syncthreads();
  for (int off = 1; off < 256; off <<= 1) {
    int u = (t >= off) ? lds[t - off] : 0;
    __syncthreads();
    lds[t] += u;
    __syncthreads();
  }
  if (t < nblk) bhD[(size_t)t * nbk + b] = lds[t] - v;  // exclusive
  if (t == 255) totD[b] = lds[255];
  __syncthreads();
  int w = (t < nblk) ? bhS[(size_t)t * nbk + b] : 0;
  lds[t] = w;
  __syncthreads();
  for (int off = 1; off < 256; off <<= 1) {
    int u = (t >= off) ? lds[t - off] : 0;
    __syncthreads();
    lds[t] += u;
    __syncthreads();
  }
  if (t < nblk) bhS[(size_t)t * nbk + b] = lds[t] - w;
  if (t == 255) totS[b] = lds[255];
}

// ---- K3: scatter edges into bucket segments (LDS cursors; in-LDS base) ----
// ebufD word: bits[23:17]=dst&127, bits[16:0]=src   (n < 2^17)
__global__ __launch_bounds__(256) void bucket_scatter(
    const int* __restrict__ src, const int* __restrict__ dst,
    const int* __restrict__ bhD, const int* __restrict__ bhS,
    const int* __restrict__ totD, const int* __restrict__ totS,
    unsigned int* __restrict__ ebufD, uint8_t* __restrict__ ebufS,
    int E, int nbk) {
  __shared__ int bD[1024], bS[1024], scanT[256];
  __shared__ int cD[1024], cS[1024];
  int k = blockIdx.x, t = threadIdx.x;
  excl_scan(totD, bD, scanT, nbk);
  excl_scan(totS, bS, scanT, nbk);
  for (int i = t; i < nbk; i += 256) {
    cD[i] = bD[i] + bhD[(size_t)k * nbk + i];
    cS[i] = bS[i] + bhS[(size_t)k * nbk + i];
  }
  __syncthreads();
  int base = k * CHUNK + t;
  for (int j = 0; j < EPT3; j++) {
    int e = base + j * 256;
    if (e < E) {
      int s = src[e], d = dst[e];
      int pD = atomicAdd(&cD[d >> BSHIFT], 1);
      ebufD[pD] = ((unsigned int)(d & (NPB - 1)) << 17) | (unsigned int)s;
      int pS = atomicAdd(&cS[s >> BSHIFT], 1);
      ebufS[pS] = (uint8_t)(s & (NPB - 1));
    }
  }
}

// ---- K4: per dst-bucket csr fill + row_start + outdeg/c_src ---------------
__global__ __launch_bounds__(256) void csr_outdeg(
    const unsigned int* __restrict__ ebufD, const uint8_t* __restrict__ ebufS,
    const int* __restrict__ totD, const int* __restrict__ totS,
    int* __restrict__ row_start, int* __restrict__ csr,
    float* __restrict__ c_src, int n, int nbk, int E) {
  __shared__ int bD[1024], bS[1024], scanT[256];
  __shared__ int cnt[NPB], sc[NPB], cur[NPB], cntS[NPB];
  int b = blockIdx.x, t = threadIdx.x;
  excl_scan(totD, bD, scanT, nbk);
  excl_scan(totS, bS, scanT, nbk);
  if (t < NPB) { cnt[t] = 0; cntS[t] = 0; }
  __syncthreads();
  int s0 = bD[b], s1 = (b + 1 < 1024) ? bD[b + 1] : E;
  for (int i = s0 + t; i < s1; i += 256) atomicAdd(&cnt[ebufD[i] >> 17], 1);
  int u0 = bS[b], u1 = (b + 1 < 1024) ? bS[b + 1] : E;
  for (int i = u0 + t; i < u1; i += 256) atomicAdd(&cntS[ebufS[i]], 1);
  __syncthreads();
  int c = (t < NPB) ? cnt[t] : 0;
  if (t < NPB) sc[t] = c;
  __syncthreads();
  for (int off = 1; off < NPB; off <<= 1) {
    int u = (t < NPB && t >= off) ? sc[t - off] : 0;
    __syncthreads();
    if (t < NPB) sc[t] += u;
    __syncthreads();
  }
  if (t < NPB) {
    int start = s0 + sc[t] - c;  // exclusive
    cur[t] = start;
    int node = b * NPB + t;
    if (node < n) {
      row_start[node] = start;
      c_src[node] = rsqrtf(fmaxf((float)cntS[t], 1.0f));
    }
  }
  if (b == 0 && t == 0) row_start[n] = E;
  __syncthreads();
  for (int i = s0 + t; i < s1; i += 256) {
    unsigned int wv = ebufD[i];
    int p = atomicAdd(&cur[wv >> 17], 1);
    csr[p] = (int)(wv & 0x1FFFFu);
  }
}

// ---------------------------------------------------------------------------
// MFMA gemm256: 64x128 tile, BK=64, 4 waves, XOR-swizzled LDS (16B chunk
// ^ row&7).  t0b[n,128](bf16) = (x[n,256] @ W0) * c_src[row].
// ---------------------------------------------------------------------------
__global__ __launch_bounds__(256) void gemm256_mfma(const float* __restrict__ x,
                                                    const ushort* __restrict__ W0t,
                                                    const float* __restrict__ c_src,
                                                    ushort* __restrict__ t0b, int n) {
  __shared__ alignas(16) ushort As[64 * 64];    // 8 KB
  __shared__ alignas(16) ushort Bs[128 * 64];   // 16 KB
  int tid = threadIdx.x;
  int row0 = blockIdx.x * 64;
  int lane = tid & 63;
  int w = tid >> 6;
  int l16 = lane & 15, hi = lane >> 4;
  f32x4 acc[8];
#pragma unroll
  for (int c = 0; c < 8; c++) acc[c] = (f32x4){0.f, 0.f, 0.f, 0.f};

  for (int kt = 0; kt < 256; kt += 64) {
    {  // stage A: row r=tid>>2, two 16B chunks; 8 fp32 -> 8 bf16 each
      int r = tid >> 2;
      int gr = row0 + r;
#pragma unroll
      for (int u = 0; u < 2; u++) {
        int c8 = (tid & 3) * 2 + u;  // 0..7
        float4 v0 = make_float4(0.f, 0.f, 0.f, 0.f), v1 = v0;
        if (gr < n) {
          v0 = ld4(&x[(size_t)gr * 256 + kt + c8 * 8]);
          v1 = ld4(&x[(size_t)gr * 256 + kt + c8 * 8 + 4]);
        }
        uint4 o;
        o.x = f2bf(v0.x) | (f2bf(v0.y) << 16);
        o.y = f2bf(v0.z) | (f2bf(v0.w) << 16);
        o.z = f2bf(v1.x) | (f2bf(v1.y) << 16);
        o.w = f2bf(v1.z) | (f2bf(v1.w) << 16);
        *(uint4*)&As[r * 64 + (c8 ^ (r & 7)) * 8] = o;
      }
    }
    {  // stage B: row r=tid>>1 (0..127), four 16B chunks from W0t (bf16)
      int r = tid >> 1;
#pragma unroll
      for (int u = 0; u < 4; u++) {
        int c8 = (tid & 1) * 4 + u;  // 0..7
        uint4 o = *(const uint4*)&W0t[(size_t)r * 256 + kt + c8 * 8];
        *(uint4*)&Bs[r * 64 + (c8 ^ (r & 7)) * 8] = o;
      }
    }
    __syncthreads();
#pragma unroll
    for (int ks = 0; ks < 2; ks++) {
      int ar = w * 16 + l16;
      int ac = ks * 4 + hi;
      short8 a = *(const short8*)&As[ar * 64 + (ac ^ (ar & 7)) * 8];
#pragma unroll
      for (int c = 0; c < 8; c++) {
        int br = c * 16 + l16;
        short8 b = *(const short8*)&Bs[br * 64 + (ac ^ (br & 7)) * 8];
        acc[c] = __builtin_amdgcn_mfma_f32_16x16x32_bf16(a, b, acc[c], 0, 0, 0);
      }
    }
    __syncthreads();
  }
  float cs[4];
#pragma unroll
  for (int r = 0; r < 4; r++) {
    int gm = row0 + w * 16 + hi * 4 + r;
    cs[r] = (gm < n) ? c_src[gm] : 0.f;
  }
#pragma unroll
  for (int c = 0; c < 8; c++)
#pragma unroll
    for (int r = 0; r < 4; r++) {
      int gm = row0 + w * 16 + hi * 4 + r;
      if (gm < n) t0b[(size_t)gm * 128 + c * 16 + l16] = (ushort)f2bf(acc[c][r] * cs[r]);
    }
}

// ---------------------------------------------------------------------------
// Layer-1 aggregation (persistent waves, R8 structure, unchanged):
// h1s = relu(agg(t0b)*cd + b0) * c_src[node]   (bf16)
// ---------------------------------------------------------------------------
__global__ __launch_bounds__(256) void agg_kernel(const ushort* __restrict__ T,
                                                  const int* __restrict__ row_start,
                                                  const int* __restrict__ csr_src,
                                                  const float* __restrict__ c_src,
                                                  const float* __restrict__ bias,
                                                  unsigned int* __restrict__ out, int n) {
  int lane = threadIdx.x & 63;
  int gw = (blockIdx.x * 256 + threadIdx.x) >> 6;
  int nw = gridDim.x * 4;
  float bx = bias[lane * 2], by = bias[lane * 2 + 1];
  for (int node = gw; node < n; node += nw) {
    int e0 = row_start[node], e1 = row_start[node + 1];
    float ax = 0.f, ay = 0.f;
    for (int eb = e0; eb < e1; eb += 64) {
      int rem = e1 - eb;
      int cnt = rem < 64 ? rem : 64;
      int msrc = (lane < rem) ? csr_src[eb + lane] : 0;
      int j = 0;
      for (; j + 7 < cnt; j += 8) {
        unsigned int w[8];
#pragma unroll
        for (int u = 0; u < 8; u++) {
          int s = __shfl(msrc, j + u);
          w[u] = *(const unsigned int*)&T[(size_t)s * 128 + lane * 2];
        }
#pragma unroll
        for (int u = 0; u < 8; u++) {
          ax += bf2f(w[u] & 0xffff);
          ay += bf2f(w[u] >> 16);
        }
      }
      for (; j + 1 < cnt; j += 2) {
        int s0 = __shfl(msrc, j), s1 = __shfl(msrc, j + 1);
        unsigned int w0 = *(const unsigned int*)&T[(size_t)s0 * 128 + lane * 2];
        unsigned int w1 = *(const unsigned int*)&T[(size_t)s1 * 128 + lane * 2];
        ax += bf2f(w0 & 0xffff) + bf2f(w1 & 0xffff);
        ay += bf2f(w0 >> 16) + bf2f(w1 >> 16);
      }
      if (j < cnt) {
        int s0 = __shfl(msrc, j);
        unsigned int w0 = *(const unsigned int*)&T[(size_t)s0 * 128 + lane * 2];
        ax += bf2f(w0 & 0xffff);
        ay += bf2f(w0 >> 16);
      }
    }
    float cd = rsqrtf(fmaxf((float)(e1 - e0), 1.0f));
    float csn = c_src[node];
    float rx = fmaxf(fmaf(ax, cd, bx), 0.f) * csn;
    float ry = fmaxf(fmaf(ay, cd, by), 0.f) * csn;
    out[(size_t)node * 64 + lane] = f2bf(rx) | (f2bf(ry) << 16);
  }
}

// ---------------------------------------------------------------------------
// agg_final: per 64-node tile, 512 threads (8 waves, 8 nodes/wave):
//   gather-aggregate h1s neighbors -> As (LDS, MFMA A-layout, swizzled)
//   h2 = As @ W1 + b1 (MFMA) -> d_out (fp32); relu(h2) -> Hs (bf16)
//   logits = Hs @ Wc + bc  (fused; 64 rows x 8 thr/row, one pass)
// LDS phases unioned: {As 16K + Bs 16K} <-> {Hs 16.6K + Wl 20K} = 36.6 KB.
// ---------------------------------------------------------------------------
#define HSTRIDE 130
__global__ __launch_bounds__(512) void agg_final(
    const ushort* __restrict__ h1s, const int* __restrict__ row_start,
    const int* __restrict__ csr_src, const ushort* __restrict__ W1t,
    const float* __restrict__ b1, const float* __restrict__ Wc,
    const float* __restrict__ bc, float* __restrict__ h_out,
    float* __restrict__ logits, int n) {
  __shared__ alignas(16) union {
    struct { ushort As[64 * 128]; ushort Bs[128 * 64]; } g;    // 32 KB
    struct { ushort Hs[64 * HSTRIDE]; float Wl[128 * 40]; } l; // 36.6 KB
  } sm;
  int tid = threadIdx.x;
  int lane = tid & 63;
  int w = tid >> 6;          // 0..7
  int l16 = lane & 15, hi = lane >> 4;
  int row0 = blockIdx.x * 64;

  // ---- gather phase: wave w aggregates nodes row0 + w*8 .. +8 ----
  for (int i = 0; i < 8; i++) {
    int rl = w * 8 + i;
    int node = row0 + rl;
    float ax = 0.f, ay = 0.f;
    if (node < n) {
      int e0 = row_start[node], e1 = row_start[node + 1];
      for (int eb = e0; eb < e1; eb += 64) {
        int rem = e1 - eb;
        int cnt = rem < 64 ? rem : 64;
        int msrc = (lane < rem) ? csr_src[eb + lane] : 0;
        int j = 0;
        for (; j + 7 < cnt; j += 8) {
          unsigned int wv[8];
#pragma unroll
          for (int u = 0; u < 8; u++) {
            int s = __shfl(msrc, j + u);
            wv[u] = *(const unsigned int*)&h1s[(size_t)s * 128 + lane * 2];
          }
#pragma unroll
          for (int u = 0; u < 8; u++) {
            ax += bf2f(wv[u] & 0xffff);
            ay += bf2f(wv[u] >> 16);
          }
        }
        for (; j < cnt; j++) {
          int s = __shfl(msrc, j);
          unsigned int wv = *(const unsigned int*)&h1s[(size_t)s * 128 + lane * 2];
          ax += bf2f(wv & 0xffff);
          ay += bf2f(wv >> 16);
        }
      }
      float cd = rsqrtf(fmaxf((float)(e1 - e0), 1.0f));
      ax *= cd;
      ay *= cd;
    }
    // store feature pair (2*lane, 2*lane+1) to As row rl, swizzled
    unsigned int pr = f2bf(ax) | (f2bf(ay) << 16);
    int ch = lane >> 2;  // 16B chunk 0..15
    *(unsigned int*)&sm.g.As[rl * 128 + ((ch ^ (rl & 7)) << 3) + ((lane & 3) << 1)] = pr;
  }
  __syncthreads();

  // ---- MFMA phase: wave w -> rows (w&3)*16..+16, cols (w>>2)*64..+64 ----
  int wr = w & 3, wc = w >> 2;
  f32x4 acc[4];
#pragma unroll
  for (int c = 0; c < 4; c++) acc[c] = (f32x4){0.f, 0.f, 0.f, 0.f};
  for (int kt = 0; kt < 128; kt += 64) {
    {  // stage Bs[128][64] from W1t cols kt..kt+64 (512 thr, 2 chunks each)
      int r = tid >> 2;
#pragma unroll
      for (int u = 0; u < 2; u++) {
        int c8 = (tid & 3) * 2 + u;
        uint4 o = *(const uint4*)&W1t[(size_t)r * 128 + kt + c8 * 8];
        *(uint4*)&sm.g.Bs[r * 64 + ((c8 ^ (r & 7)) << 3)] = o;
      }
    }
    __syncthreads();
#pragma unroll
    for (int ks = 0; ks < 2; ks++) {
      int ar = wr * 16 + l16;
      int ch = (kt >> 3) + ks * 4 + hi;  // global 16B chunk 0..15
      short8 a = *(const short8*)&sm.g.As[ar * 128 + ((ch ^ (ar & 7)) << 3)];
#pragma unroll
      for (int c = 0; c < 4; c++) {
        int br = wc * 64 + c * 16 + l16;
        short8 b = *(const short8*)&sm.g.Bs[br * 64 + (((ks * 4 + hi) ^ (br & 7)) << 3)];
        acc[c] = __builtin_amdgcn_mfma_f32_16x16x32_bf16(a, b, acc[c], 0, 0, 0);
      }
    }
    __syncthreads();  // Bs reuse / As->Hs alias safety
  }

  // ---- epilogue: h2 -> d_out (fp32); relu(h2) bf16 -> Hs; load Wl ----
#pragma unroll
  for (int c = 0; c < 4; c++) {
    int col = wc * 64 + c * 16 + l16;
    float bb = b1[col];
#pragma unroll
    for (int r = 0; r < 4; r++) {
      int rl = wr * 16 + hi * 4 + r;
      int gm = row0 + rl;
      float h2 = acc[c][r] + bb;
      if (gm < n) h_out[(size_t)gm * 128 + col] = h2;
      sm.l.Hs[rl * HSTRIDE + col] = (ushort)f2bf(fmaxf(h2, 0.f));
    }
  }
  for (int i = tid; i < 128 * 40; i += 512) sm.l.Wl[i] = Wc[i];
  __syncthreads();

  // ---- logits: 64 rows x 8 threads/row, 5 outputs each ----
  int rl = tid >> 3, cg = tid & 7;
  int gm = row0 + rl;
  if (gm < n) {
    float a5[5] = {0.f, 0.f, 0.f, 0.f, 0.f};
    for (int k = 0; k < 128; k++) {
      float v = bf2f(sm.l.Hs[rl * HSTRIDE + k]);
#pragma unroll
      for (int j = 0; j < 5; j++) a5[j] = fmaf(v, sm.l.Wl[k * 40 + cg * 5 + j], a5[j]);
    }
#pragma unroll
    for (int j = 0; j < 5; j++)
      logits[(size_t)gm * 40 + cg * 5 + j] = a5[j] + bc[cg * 5 + j];
  }
}

extern "C" void kernel_launch(void* const* d_in, const int* in_sizes, int n_in,
                              void* d_out, int out_size, void* d_ws, size_t ws_size,
                              hipStream_t stream) {
  const float* x = (const float*)d_in[0];
  const int* src = (const int*)d_in[1];
  const int* dst = (const int*)d_in[2];
  const float* W0 = (const float*)d_in[3];
  const float* b0 = (const float*)d_in[4];
  const float* W1 = (const float*)d_in[5];
  const float* b1 = (const float*)d_in[6];
  const float* Wc = (const float*)d_in[7];
  const float* bc = (const float*)d_in[8];
  const int n = in_sizes[0] / 256;
  const int E = in_sizes[1];
  const int nbk = (n + NPB - 1) >> BSHIFT;          // 782 (<=1024)
  const int nblk = (E + CHUNK - 1) / CHUNK;         // 250 (<=256)

  char* wsp = (char*)d_ws;
  auto alloc = [&](size_t bytes) -> char* {
    char* p = wsp;
    wsp += (bytes + 255) & ~(size_t)255;
    return p;
  };
  ushort* t0b = (ushort*)alloc((size_t)n * 128 * sizeof(ushort));
  ushort* h1s = (ushort*)alloc((size_t)n * 128 * sizeof(ushort));
  float* c_src = (float*)alloc((size_t)n * sizeof(float));
  ushort* W0t = (ushort*)alloc((size_t)128 * 256 * sizeof(ushort));
  ushort* W1t = (ushort*)alloc((size_t)128 * 128 * sizeof(ushort));
  int* bhD = (int*)alloc((size_t)nblk * nbk * sizeof(int));
  int* bhS = (int*)alloc((size_t)nblk * nbk * sizeof(int));
  int* totD = (int*)alloc((size_t)nbk * sizeof(int));
  int* totS = (int*)alloc((size_t)nbk * sizeof(int));
  unsigned int* ebufD = (unsigned int*)alloc((size_t)E * sizeof(unsigned int));
  uint8_t* ebufS = (uint8_t*)alloc((size_t)E);
  int* row_start = (int*)alloc((size_t)(n + 1) * sizeof(int));
  int* csr = (int*)alloc((size_t)E * sizeof(int));

  float* h_out = (float*)d_out;             // n x 128 (h2)
  float* logits = h_out + (size_t)n * 128;  // n x 40

  // 1) hist (blocks 0..nblk) + weight prep (blocks nblk..nblk+128)
  hist_prep<<<nblk + 128, 256, 0, stream>>>(src, dst, W0, W1, W0t, W1t,
                                            bhD, bhS, E, nbk, nblk);
  // 2) per-bucket cross-block scan
  bucket_scan_blocks<<<nbk, 256, 0, stream>>>(bhD, bhS, totD, totS, nbk, nblk);
  // 3) scatter (computes bucket bases in-LDS from totD/totS)
  bucket_scatter<<<nblk, 256, 0, stream>>>(src, dst, bhD, bhS, totD, totS,
                                           ebufD, ebufS, E, nbk);
  // 4) csr fill + row_start + c_src (in-LDS bases)
  csr_outdeg<<<nbk, 256, 0, stream>>>(ebufD, ebufS, totD, totS,
                                      row_start, csr, c_src, n, nbk, E);
  // 5) t0b(bf16) = (x @ W0) * c_src[row]
  gemm256_mfma<<<(n + 63) / 64, 256, 0, stream>>>(x, W0t, c_src, t0b, n);
  // 6) h1s(bf16) = relu(agg(t0b) * cd + b0) * c_src[node]
  agg_kernel<<<2048, 256, 0, stream>>>(t0b, row_start, csr, c_src, b0,
                                       (unsigned int*)h1s, n);
  // 7) fused: aggregate h1s -> LDS -> h2 = @W1 + b1 (d_out) -> logits
  agg_final<<<(n + 63) / 64, 512, 0, stream>>>(h1s, row_start, csr, W1t, b1,
                                               Wc, bc, h_out, logits, n);
}